// Round 8
// baseline (10501.147 us; speedup 1.0000x reference)
//
#include <hip/hip_runtime.h>
#include <float.h>

#define NPIX 16384    // B*H*W pixels
#define NE   8192     // codebook entries
#define KD   256      // channels
#define HW   1024
#define BCHW 262144
#define NT   8        // N-tiles (128 codes) per wg -> wg spans 1024 codes
#define CAND_CAP 393216u
#define DELTA 2.5e-4f // emission/filter window: bf16 err + 2x key quant + e2 spread
#define KMASK 0xFFFFE000u

typedef __attribute__((ext_vector_type(8))) short short8;
typedef __attribute__((ext_vector_type(4))) short short4v;
typedef __attribute__((ext_vector_type(4))) float f32x4;
typedef unsigned long long u64;
typedef unsigned int u32;

__device__ __forceinline__ u32 fkey(float f) {
    u32 u = __float_as_uint(f);
    return u ^ ((u >> 31) ? 0xFFFFFFFFu : 0x80000000u);
}
__device__ __forceinline__ short bf16rne(float f) {
    u32 u = __float_as_uint(f);
    u += 0x7FFFu + ((u >> 16) & 1u);
    return (short)(u >> 16);
}
__device__ __forceinline__ float kval(u32 pk) {   // packed key -> quantized value
    return __uint_as_float(pk & KMASK);
}

#define GLDS(gp, lp) __builtin_amdgcn_global_load_lds( \
    (const __attribute__((address_space(1))) void*)(gp), \
    (__attribute__((address_space(3))) void*)(lp), 16, 0, 0)

// ---------------------------------------------------------------------------
// prep: codebook -> bf16 AND e2[n] = ||e_n||^2. One wave per row.
// ---------------------------------------------------------------------------
__global__ void vq_prep(const float* __restrict__ cb, short* __restrict__ eh,
                        float* __restrict__ e2) {
    const int row  = (blockIdx.x * 256 + threadIdx.x) >> 6;
    const int lane = threadIdx.x & 63;
    const f32x4 v = *(const f32x4*)(cb + (size_t)row * KD + lane * 4);
    short4v h;
    h[0] = bf16rne(v[0]); h[1] = bf16rne(v[1]);
    h[2] = bf16rne(v[2]); h[3] = bf16rne(v[3]);
    *(short4v*)(eh + (size_t)row * KD + lane * 4) = h;
    float s = v[0]*v[0] + v[1]*v[1] + v[2]*v[2] + v[3]*v[3];
    #pragma unroll
    for (int m = 1; m < 64; m <<= 1) s += __shfl_xor(s, m);
    if (lane == 0) e2[row] = s;
}

// ---------------------------------------------------------------------------
// z [b][k][hw] fp32 -> zh [p][k] bf16 (transpose via LDS)
// ---------------------------------------------------------------------------
__global__ void vq_zh(const float* __restrict__ z, short* __restrict__ zh) {
    __shared__ float ts[64][65];
    const int b   = blockIdx.z;
    const int k0  = blockIdx.y * 64;
    const int hw0 = blockIdx.x * 64;
    const int tid = threadIdx.x;
    const int pl  = tid & 63, kk = tid >> 6;
    #pragma unroll
    for (int i = 0; i < 16; ++i) {
        const int k = kk + 4 * i;
        ts[k][pl] = z[b * BCHW + (k0 + k) * HW + hw0 + pl];
    }
    __syncthreads();
    const int tx = tid & 15, ty = tid >> 4;
    #pragma unroll
    for (int j = 0; j < 4; ++j) {
        const int p = ty + 16 * j;
        short4v v;
        #pragma unroll
        for (int q = 0; q < 4; ++q) v[q] = bf16rne(ts[tx * 4 + q][p]);
        *(short4v*)(zh + (size_t)(b * HW + hw0 + p) * KD + k0 + tx * 4) = v;
    }
}

// ---------------------------------------------------------------------------
// Single-pass fused GEMM + argmin + candidate collection (unchanged from R7).
// ---------------------------------------------------------------------------
__global__ __launch_bounds__(256) void vq_gemm(
    const short* __restrict__ zh, const short* __restrict__ eh,
    u32* __restrict__ grunmin, u32* __restrict__ flags,
    u64* __restrict__ cand, u32* __restrict__ ncand)
{
    __shared__ short As[2][4096];   // [buf][128 rows x 32 k]
    __shared__ short Bs[2][4096];

    const int tid  = threadIdx.x;
    const int lane = tid & 63;
    const int w    = tid >> 6;
    const int wm   = w >> 1, wn = w & 1;
    const int p0   = blockIdx.y * 128;
    const int nb0  = blockIdx.x * (NT * 128);

    const int sr = lane >> 2;
    const int ss = (lane & 3) ^ ((sr >> 1) & 3);
    const int q   = lane >> 4;
    const int rsw = ((lane & 15) >> 1) & 3;

    u32 b1[4][4], b2[4][4];
    #pragma unroll
    for (int m = 0; m < 4; ++m)
        #pragma unroll
        for (int r = 0; r < 4; ++r) { b1[m][r] = 0xFFFFFFFFu; b2[m][r] = 0xFFFFFFFFu; }

    #define STAGE(nt_, t_, buf_) do {                                          \
        const int k0_ = (t_) * 32;                                             \
        const int n0_ = nb0 + (nt_) * 128;                                     \
        _Pragma("unroll")                                                      \
        for (int i_ = 0; i_ < 2; ++i_) {                                       \
            const int rb_ = w * 32 + i_ * 16;                                  \
            GLDS(zh + (size_t)(p0 + rb_ + sr) * KD + k0_ + ss * 8,             \
                 &As[buf_][rb_ * 32]);                                         \
            GLDS(eh + (size_t)(n0_ + rb_ + sr) * KD + k0_ + ss * 8,            \
                 &Bs[buf_][rb_ * 32]);                                         \
        }                                                                      \
    } while (0)

    f32x4 acc[4][4];

    STAGE(0, 0, 0);
    __syncthreads();

    #pragma unroll 1
    for (int nt = 0; nt < NT; ++nt) {
        #pragma unroll
        for (int m = 0; m < 4; ++m)
            #pragma unroll
            for (int nf = 0; nf < 4; ++nf)
                acc[m][nf] = (f32x4){0.f, 0.f, 0.f, 0.f};

        #pragma unroll
        for (int t = 0; t < 8; ++t) {
            const int buf = t & 1;
            if (t < 7)            { STAGE(nt, t + 1, buf ^ 1); }
            else if (nt + 1 < NT) { STAGE(nt + 1, 0, buf ^ 1); }

            short8 af[4], bfv[4];
            #pragma unroll
            for (int m = 0; m < 4; ++m) {
                const int row = wm * 64 + m * 16 + (lane & 15);
                af[m] = *(const short8*)&As[buf][row * 32 + ((q ^ rsw) * 8)];
            }
            #pragma unroll
            for (int nf = 0; nf < 4; ++nf) {
                const int row = wn * 64 + nf * 16 + (lane & 15);
                bfv[nf] = *(const short8*)&Bs[buf][row * 32 + ((q ^ rsw) * 8)];
            }
            #pragma unroll
            for (int m = 0; m < 4; ++m)
                #pragma unroll
                for (int nf = 0; nf < 4; ++nf)
                    acc[m][nf] = __builtin_amdgcn_mfma_f32_16x16x32_bf16(
                        af[m], bfv[nf], acc[m][nf], 0, 0, 0);

            if (t == 7) {
                const u32 nbase = (u32)(nb0 + nt * 128 + wn * 64 + (lane & 15));
                #pragma unroll
                for (int m = 0; m < 4; ++m) {
                    #pragma unroll
                    for (int r = 0; r < 4; ++r) {
                        u32 pk0 = (__float_as_uint(0.0625f - acc[m][0][r]) & KMASK) | (nbase);
                        u32 pk1 = (__float_as_uint(0.0625f - acc[m][1][r]) & KMASK) | (nbase + 16u);
                        u32 pk2 = (__float_as_uint(0.0625f - acc[m][2][r]) & KMASK) | (nbase + 32u);
                        u32 pk3 = (__float_as_uint(0.0625f - acc[m][3][r]) & KMASK) | (nbase + 48u);
                        const u32 lo01 = min(pk0, pk1), hi01 = max(pk0, pk1);
                        const u32 lo23 = min(pk2, pk3), hi23 = max(pk2, pk3);
                        const u32 m1 = min(lo01, lo23);
                        const u32 m2 = min(max(lo01, lo23), min(hi01, hi23));
                        const u32 nb1 = min(b1[m][r], m1);
                        const u32 nb2 = min(max(b1[m][r], m1), min(b2[m][r], m2));
                        b1[m][r] = nb1; b2[m][r] = nb2;
                    }
                }
            }
            __syncthreads();
        }
    }
    #undef STAGE

    u32 bmin[4][4];
    #pragma unroll
    for (int m = 0; m < 4; ++m)
        #pragma unroll
        for (int r = 0; r < 4; ++r) {
            u32 v = b1[m][r];
            #pragma unroll
            for (int msk = 1; msk < 16; msk <<= 1)
                v = min(v, (u32)__shfl_xor((int)v, msk));
            bmin[m][r] = v;
        }

    const int g = lane >> 4;
    if ((lane & 15) == 0) {
        #pragma unroll
        for (int m = 0; m < 4; ++m)
            #pragma unroll
            for (int r = 0; r < 4; ++r)
                atomicMin(&grunmin[p0 + wm * 64 + m * 16 + g * 4 + r], bmin[m][r]);
    }

    u32 c = 0;
    #pragma unroll
    for (int m = 0; m < 4; ++m)
        #pragma unroll
        for (int r = 0; r < 4; ++r) {
            const float thr = kval(bmin[m][r]) + DELTA;
            c += (kval(b1[m][r]) <= thr) ? 1u : 0u;
            c += (kval(b2[m][r]) <= thr) ? 1u : 0u;
        }

    u32 pre = c;
    #pragma unroll
    for (int d = 1; d < 64; d <<= 1) {
        const u32 t = (u32)__shfl_up((int)pre, d);
        if (lane >= d) pre += t;
    }
    const u32 total = (u32)__shfl((int)pre, 63);
    u32 base = 0;
    if (lane == 63) base = atomicAdd(ncand, total);
    base = (u32)__shfl((int)base, 63);
    u32 off = base + pre - c;

    #pragma unroll
    for (int m = 0; m < 4; ++m)
        #pragma unroll
        for (int r = 0; r < 4; ++r) {
            const int prow = p0 + wm * 64 + m * 16 + g * 4 + r;
            const float thr = kval(bmin[m][r]) + DELTA;
            if (kval(b1[m][r]) <= thr) {
                if (off < CAND_CAP) cand[off] = ((u64)(u32)prow << 32) | b1[m][r];
                else flags[prow] = 0u;
                ++off;
            }
            if (kval(b2[m][r]) <= thr) {
                if (off < CAND_CAP) cand[off] = ((u64)(u32)prow << 32) | b2[m][r];
                else flags[prow] = 0u;
                ++off;
            }
        }
}

// ---------------------------------------------------------------------------
// filter: keep candidates within converged grunmin+DELTA, compact into
// per-pixel slot arrays (slots[p][8], pcnt[p]). >8 passers -> flag pixel.
// ---------------------------------------------------------------------------
__global__ void vq_filter(const u32* __restrict__ grunmin,
                          const u64* __restrict__ cand,
                          const u32* __restrict__ ncand,
                          u32* __restrict__ pcnt, u32* __restrict__ slots,
                          u32* __restrict__ flags)
{
    const u32 nc = min(*ncand, CAND_CAP);
    for (u32 i = blockIdx.x * 256 + threadIdx.x; i < nc; i += gridDim.x * 256) {
        const u64 e = cand[i];
        const int p = (int)(e >> 32);
        const u32 pk = (u32)e;
        if (kval(pk) > kval(grunmin[p]) + DELTA) continue;
        const u32 pos = atomicAdd(&pcnt[p], 1u);
        if (pos < 8u) slots[p * 8 + pos] = pk & 8191u;
        else flags[p] = 0u;
    }
}

// ---------------------------------------------------------------------------
// exact: one wg per 16 consecutive pixels.
//  pcnt==1  -> winner direct (no z traffic).
//  pcnt 2..8 -> stage z block [16][260] in LDS coalesced; one wave per
//               candidate does the exact fp32 dot (z LDS, cb L2).
//  flagged  -> full-scan fallback (never in practice).
// ---------------------------------------------------------------------------
__global__ __launch_bounds__(256) void vq_exact(
    const float* __restrict__ z, const float* __restrict__ cb,
    const float* __restrict__ e2, const u32* __restrict__ pcnt,
    const u32* __restrict__ slots, const u32* __restrict__ flags,
    u64* __restrict__ final_)
{
    __shared__ float zb[16][260];
    __shared__ u32 work[128];      // (pix<<16) | n
    __shared__ int nwork;

    const int tid = threadIdx.x;
    const int g0  = blockIdx.x * 16;
    const int bb  = g0 >> 10, hw0 = g0 & 1023;

    if (tid == 0) nwork = 0;
    __syncthreads();
    if (tid < 16) {
        const int p = g0 + tid;
        if (flags[p] != 0u) {                 // not overflow-flagged
            const u32 c = pcnt[p];
            if (c == 1u) {
                final_[p] = (u64)slots[p * 8];     // key 0 -> wins, no dot needed
            } else if (c >= 2u) {              // c <= 8 guaranteed (else flagged)
                const int base = atomicAdd(&nwork, (int)c);
                for (u32 i = 0; i < c; ++i)
                    work[base + i] = ((u32)tid << 16) | slots[p * 8 + i];
            }
        }
    }
    __syncthreads();
    const int nw = nwork;
    if (nw > 0) {
        #pragma unroll
        for (int i = 0; i < 16; ++i) {
            const int idx = i * 256 + tid;
            const int c = idx >> 4, pix = idx & 15;
            zb[pix][c] = z[(size_t)bb * BCHW + (size_t)c * HW + hw0 + pix];
        }
        __syncthreads();
        const int wv = tid >> 6, lane = tid & 63;
        for (int wi = wv; wi < nw; wi += 4) {
            const u32 e = work[wi];
            const int pix = (int)(e >> 16), n = (int)(e & 0xFFFFu);
            const f32x4 zv = *(const f32x4*)&zb[pix][lane * 4];
            const f32x4 ev = *(const f32x4*)(cb + (size_t)n * KD + lane * 4);
            float part = zv[0]*ev[0] + zv[1]*ev[1] + zv[2]*ev[2] + zv[3]*ev[3];
            #pragma unroll
            for (int m = 1; m < 64; m <<= 1) part += __shfl_xor(part, m);
            if (lane == 0) {
                const float s = 0.5f * e2[n] - part;
                atomicMin(&final_[g0 + pix], ((u64)fkey(s) << 32) | (u32)n);
            }
        }
    }

    // overflow fallback: exact scan of all codes for flagged pixels
    const int gwv = (blockIdx.x * 256 + tid) >> 6;
    const int lane = tid & 63;
    const int nwv = gridDim.x * 4;
    for (int p = gwv; p < NPIX; p += nwv) {
        if (flags[p] != 0u) continue;
        const int b2_ = p >> 10, hw = p & 1023;
        const float* zp = z + b2_ * BCHW + hw;
        float bd = FLT_MAX; int bn = 0;
        for (int n = lane; n < NE; n += 64) {
            float s = 0.f;
            for (int k = 0; k < KD; ++k) s += zp[k * HW] * cb[(size_t)n * KD + k];
            s = 0.5f * e2[n] - s;
            if (s < bd) { bd = s; bn = n; }
        }
        #pragma unroll
        for (int msk = 1; msk < 64; msk <<= 1) {
            const float od = __shfl_xor(bd, msk);
            const int   on = __shfl_xor(bn, msk);
            if (od < bd || (od == bd && on < bn)) { bd = od; bn = on; }
        }
        if (lane == 0) atomicMin(&final_[p], ((u64)fkey(bd) << 32) | (u32)bn);
    }
}

// ---------------------------------------------------------------------------
// Output kernel, tile-transposed (unchanged from R7).
// ---------------------------------------------------------------------------
__global__ __launch_bounds__(256) void vq_out_kernel(
    const float* __restrict__ z, const float* __restrict__ cb,
    const u64* __restrict__ final_, float* __restrict__ out,
    float* __restrict__ idxf, float* __restrict__ loss)
{
    __shared__ float zq[32][257];
    __shared__ int   nidx[32];

    const int tid = threadIdx.x;
    const int p0  = blockIdx.x * 32;
    const int bb  = p0 >> 10;
    const int hw0 = p0 & 1023;

    if (tid < 32) {
        const int n = (int)((u32)final_[p0 + tid] & 8191u);
        nidx[tid] = n;
        idxf[p0 + tid] = (float)n;
    }
    __syncthreads();

    {
        const int r = tid >> 3, i = tid & 7;
        const float* src = cb + (size_t)nidx[r] * KD;
        #pragma unroll
        for (int j = 0; j < 8; ++j) {
            const int col = i * 4 + j * 32;
            const f32x4 v = *(const f32x4*)(src + col);
            zq[r][col + 0] = v[0]; zq[r][col + 1] = v[1];
            zq[r][col + 2] = v[2]; zq[r][col + 3] = v[3];
        }
    }
    __syncthreads();

    const int p4 = (tid & 7) * 4;
    const int cg = tid >> 3;
    float ls = 0.f;
    #pragma unroll
    for (int ii = 0; ii < 8; ++ii) {
        const int c = cg + 32 * ii;
        const size_t e = (size_t)bb * BCHW + (size_t)c * HW + hw0 + p4;
        const f32x4 zv = *(const f32x4*)(z + e);
        f32x4 v;
        v[0] = zq[p4 + 0][c]; v[1] = zq[p4 + 1][c];
        v[2] = zq[p4 + 2][c]; v[3] = zq[p4 + 3][c];
        *(f32x4*)(out + e) = v;
        const float d0 = v[0] - zv[0], d1 = v[1] - zv[1];
        const float d2 = v[2] - zv[2], d3 = v[3] - zv[3];
        ls += d0 * d0 + d1 * d1 + d2 * d2 + d3 * d3;
    }
    #pragma unroll
    for (int m = 1; m < 64; m <<= 1) ls += __shfl_xor(ls, m);
    if ((tid & 63) == 0) atomicAdd(loss, ls * (1.25f / 4194304.f));
}

// ---------------------------------------------------------------------------
extern "C" void kernel_launch(void* const* d_in, const int* in_sizes, int n_in,
                              void* d_out, int out_size, void* d_ws, size_t ws_size,
                              hipStream_t stream) {
    const float* z  = (const float*)d_in[0];
    const float* cb = (const float*)d_in[1];
    float* out  = (float*)d_out;
    float* idxf = out + 4194304;
    float* loss = out + 4210688;
    // scratch inside the z_q region of d_out (fully overwritten at the end):
    char* ob = (char*)d_out;
    short* zh    = (short*)ob;                    // [0 .. 8MB)   bf16 z [p][k]
    short* eh    = (short*)(ob + 8388608);        // [8 .. 12MB)  bf16 codebook
    u64*   cand  = (u64*)(ob + 12582912);         // [12 .. 15MB) 393216 slots
    u32*   slots = (u32*)(ob + 15728640);         // [15 .. 15.5MB) 16384x8 u32
    u32*   pcnt  = (u32*)(ob + 16252928);         // [15.5 .. 15.5625MB)

    char* ws = (char*)d_ws;
    u32*   grunmin = (u32*)ws;               // 64 KB  @ 0
    u32*   flags   = (u32*)(ws + 65536);     // 64 KB
    u64*   final_  = (u64*)(ws + 131072);    // 128 KB
    float* e2      = (float*)(ws + 262144);  // 32 KB
    u32*   ncand   = (u32*)(ws + 294912);    // 4 B

    hipMemsetAsync(ws, 0xFF, 262144, stream);       // grunmin+flags+final_
    hipMemsetAsync(ncand, 0, 4, stream);
    hipMemsetAsync(pcnt, 0, 65536, stream);
    hipMemsetAsync(loss, 0, 4, stream);

    vq_prep<<<2048, 256, 0, stream>>>(cb, eh, e2);
    vq_zh<<<dim3(16, 4, 16), 256, 0, stream>>>(z, zh);
    vq_gemm<<<dim3(NE / (NT * 128), NPIX / 128), 256, 0, stream>>>(
        zh, eh, grunmin, flags, cand, ncand);
    vq_filter<<<256, 256, 0, stream>>>(grunmin, cand, ncand, pcnt, slots, flags);
    vq_exact<<<NPIX / 16, 256, 0, stream>>>(z, cb, e2, pcnt, slots, flags, final_);
    vq_out_kernel<<<NPIX / 32, 256, 0, stream>>>(z, cb, final_, out, idxf, loss);
}

// Round 9
// 1675.138 us; speedup vs baseline: 6.2688x; 6.2688x over previous
//
#include <hip/hip_runtime.h>
#include <float.h>

#define NPIX 16384    // B*H*W pixels
#define NE   8192     // codebook entries
#define KD   256      // channels
#define HW   1024
#define BCHW 262144
#define NT   8        // N-tiles (128 codes) per wg -> wg spans 1024 codes
#define CAND_CAP 524288u
#define DELTA 2.5e-4f // emission/filter window: bf16 err + 2x key quant + e2 spread
#define KMASK 0xFFFFE000u

typedef __attribute__((ext_vector_type(8))) short short8;
typedef __attribute__((ext_vector_type(4))) short short4v;
typedef __attribute__((ext_vector_type(4))) float f32x4;
typedef unsigned long long u64;
typedef unsigned int u32;

__device__ __forceinline__ u32 fkey(float f) {
    u32 u = __float_as_uint(f);
    return u ^ ((u >> 31) ? 0xFFFFFFFFu : 0x80000000u);
}
__device__ __forceinline__ short bf16rne(float f) {
    u32 u = __float_as_uint(f);
    u += 0x7FFFu + ((u >> 16) & 1u);
    return (short)(u >> 16);
}
__device__ __forceinline__ float kval(u32 pk) {   // packed key -> quantized value
    return __uint_as_float(pk & KMASK);
}

#define GLDS(gp, lp) __builtin_amdgcn_global_load_lds( \
    (const __attribute__((address_space(1))) void*)(gp), \
    (__attribute__((address_space(3))) void*)(lp), 16, 0, 0)

// ---------------------------------------------------------------------------
// prep: codebook -> bf16 AND e2[n] = ||e_n||^2. One wave per row.
// ---------------------------------------------------------------------------
__global__ void vq_prep(const float* __restrict__ cb, short* __restrict__ eh,
                        float* __restrict__ e2) {
    const int row  = (blockIdx.x * 256 + threadIdx.x) >> 6;
    const int lane = threadIdx.x & 63;
    const f32x4 v = *(const f32x4*)(cb + (size_t)row * KD + lane * 4);
    short4v h;
    h[0] = bf16rne(v[0]); h[1] = bf16rne(v[1]);
    h[2] = bf16rne(v[2]); h[3] = bf16rne(v[3]);
    *(short4v*)(eh + (size_t)row * KD + lane * 4) = h;
    float s = v[0]*v[0] + v[1]*v[1] + v[2]*v[2] + v[3]*v[3];
    #pragma unroll
    for (int m = 1; m < 64; m <<= 1) s += __shfl_xor(s, m);
    if (lane == 0) e2[row] = s;
}

// ---------------------------------------------------------------------------
// z [b][k][hw] fp32 -> zh [p][k] bf16 (transpose via LDS)
// ---------------------------------------------------------------------------
__global__ void vq_zh(const float* __restrict__ z, short* __restrict__ zh) {
    __shared__ float ts[64][65];
    const int b   = blockIdx.z;
    const int k0  = blockIdx.y * 64;
    const int hw0 = blockIdx.x * 64;
    const int tid = threadIdx.x;
    const int pl  = tid & 63, kk = tid >> 6;
    #pragma unroll
    for (int i = 0; i < 16; ++i) {
        const int k = kk + 4 * i;
        ts[k][pl] = z[b * BCHW + (k0 + k) * HW + hw0 + pl];
    }
    __syncthreads();
    const int tx = tid & 15, ty = tid >> 4;
    #pragma unroll
    for (int j = 0; j < 4; ++j) {
        const int p = ty + 16 * j;
        short4v v;
        #pragma unroll
        for (int q = 0; q < 4; ++q) v[q] = bf16rne(ts[tx * 4 + q][p]);
        *(short4v*)(zh + (size_t)(b * HW + hw0 + p) * KD + k0 + tx * 4) = v;
    }
}

// ---------------------------------------------------------------------------
// Single-pass fused GEMM + argmin + candidate collection.
// Emission bound now folds in the published global per-pixel min (grunmin),
// so non-competitive wgs emit nothing.
// ---------------------------------------------------------------------------
__global__ __launch_bounds__(256) void vq_gemm(
    const short* __restrict__ zh, const short* __restrict__ eh,
    u32* __restrict__ grunmin, u32* __restrict__ flags,
    u64* __restrict__ cand, u32* __restrict__ ncand)
{
    __shared__ short As[2][4096];   // [buf][128 rows x 32 k]
    __shared__ short Bs[2][4096];

    const int tid  = threadIdx.x;
    const int lane = tid & 63;
    const int w    = tid >> 6;
    const int wm   = w >> 1, wn = w & 1;
    const int p0   = blockIdx.y * 128;
    const int nb0  = blockIdx.x * (NT * 128);

    const int sr = lane >> 2;
    const int ss = (lane & 3) ^ ((sr >> 1) & 3);
    const int q   = lane >> 4;
    const int rsw = ((lane & 15) >> 1) & 3;

    u32 b1[4][4], b2[4][4];
    #pragma unroll
    for (int m = 0; m < 4; ++m)
        #pragma unroll
        for (int r = 0; r < 4; ++r) { b1[m][r] = 0xFFFFFFFFu; b2[m][r] = 0xFFFFFFFFu; }

    #define STAGE(nt_, t_, buf_) do {                                          \
        const int k0_ = (t_) * 32;                                             \
        const int n0_ = nb0 + (nt_) * 128;                                     \
        _Pragma("unroll")                                                      \
        for (int i_ = 0; i_ < 2; ++i_) {                                       \
            const int rb_ = w * 32 + i_ * 16;                                  \
            GLDS(zh + (size_t)(p0 + rb_ + sr) * KD + k0_ + ss * 8,             \
                 &As[buf_][rb_ * 32]);                                         \
            GLDS(eh + (size_t)(n0_ + rb_ + sr) * KD + k0_ + ss * 8,            \
                 &Bs[buf_][rb_ * 32]);                                         \
        }                                                                      \
    } while (0)

    f32x4 acc[4][4];

    STAGE(0, 0, 0);
    __syncthreads();

    #pragma unroll 1
    for (int nt = 0; nt < NT; ++nt) {
        #pragma unroll
        for (int m = 0; m < 4; ++m)
            #pragma unroll
            for (int nf = 0; nf < 4; ++nf)
                acc[m][nf] = (f32x4){0.f, 0.f, 0.f, 0.f};

        #pragma unroll
        for (int t = 0; t < 8; ++t) {
            const int buf = t & 1;
            if (t < 7)            { STAGE(nt, t + 1, buf ^ 1); }
            else if (nt + 1 < NT) { STAGE(nt + 1, 0, buf ^ 1); }

            short8 af[4], bfv[4];
            #pragma unroll
            for (int m = 0; m < 4; ++m) {
                const int row = wm * 64 + m * 16 + (lane & 15);
                af[m] = *(const short8*)&As[buf][row * 32 + ((q ^ rsw) * 8)];
            }
            #pragma unroll
            for (int nf = 0; nf < 4; ++nf) {
                const int row = wn * 64 + nf * 16 + (lane & 15);
                bfv[nf] = *(const short8*)&Bs[buf][row * 32 + ((q ^ rsw) * 8)];
            }
            #pragma unroll
            for (int m = 0; m < 4; ++m)
                #pragma unroll
                for (int nf = 0; nf < 4; ++nf)
                    acc[m][nf] = __builtin_amdgcn_mfma_f32_16x16x32_bf16(
                        af[m], bfv[nf], acc[m][nf], 0, 0, 0);

            if (t == 7) {
                const u32 nbase = (u32)(nb0 + nt * 128 + wn * 64 + (lane & 15));
                #pragma unroll
                for (int m = 0; m < 4; ++m) {
                    #pragma unroll
                    for (int r = 0; r < 4; ++r) {
                        u32 pk0 = (__float_as_uint(0.0625f - acc[m][0][r]) & KMASK) | (nbase);
                        u32 pk1 = (__float_as_uint(0.0625f - acc[m][1][r]) & KMASK) | (nbase + 16u);
                        u32 pk2 = (__float_as_uint(0.0625f - acc[m][2][r]) & KMASK) | (nbase + 32u);
                        u32 pk3 = (__float_as_uint(0.0625f - acc[m][3][r]) & KMASK) | (nbase + 48u);
                        const u32 lo01 = min(pk0, pk1), hi01 = max(pk0, pk1);
                        const u32 lo23 = min(pk2, pk3), hi23 = max(pk2, pk3);
                        const u32 m1 = min(lo01, lo23);
                        const u32 m2 = min(max(lo01, lo23), min(hi01, hi23));
                        const u32 nb1 = min(b1[m][r], m1);
                        const u32 nb2 = min(max(b1[m][r], m1), min(b2[m][r], m2));
                        b1[m][r] = nb1; b2[m][r] = nb2;
                    }
                }
            }
            __syncthreads();
        }
    }
    #undef STAGE

    // ---- wg-end: per-pixel local bound via 16-lane min-fold of b1 ----
    u32 bmin[4][4];
    #pragma unroll
    for (int m = 0; m < 4; ++m)
        #pragma unroll
        for (int r = 0; r < 4; ++r) {
            u32 v = b1[m][r];
            #pragma unroll
            for (int msk = 1; msk < 16; msk <<= 1)
                v = min(v, (u32)__shfl_xor((int)v, msk));
            bmin[m][r] = v;
        }

    // publish per-pixel slice-min (distributed atomics, 16/wave)
    const int g = lane >> 4;
    if ((lane & 15) == 0) {
        #pragma unroll
        for (int m = 0; m < 4; ++m)
            #pragma unroll
            for (int r = 0; r < 4; ++r)
                atomicMin(&grunmin[p0 + wm * 64 + m * 16 + g * 4 + r], bmin[m][r]);
    }

    // read back the (partially converged) global bound; >= final grunmin,
    // so emission stays a superset of the final filter set.
    float thrv[4][4];
    #pragma unroll
    for (int m = 0; m < 4; ++m)
        #pragma unroll
        for (int r = 0; r < 4; ++r) {
            const int prow = p0 + wm * 64 + m * 16 + g * 4 + r;
            const u32 gb = grunmin[prow];
            thrv[m][r] = kval(min(bmin[m][r], gb)) + DELTA;
        }

    // count emissions
    u32 c = 0;
    #pragma unroll
    for (int m = 0; m < 4; ++m)
        #pragma unroll
        for (int r = 0; r < 4; ++r) {
            c += (kval(b1[m][r]) <= thrv[m][r]) ? 1u : 0u;
            c += (kval(b2[m][r]) <= thrv[m][r]) ? 1u : 0u;
        }

    // wave prefix scan + single ncand atomic per wave
    u32 pre = c;
    #pragma unroll
    for (int d = 1; d < 64; d <<= 1) {
        const u32 t = (u32)__shfl_up((int)pre, d);
        if (lane >= d) pre += t;
    }
    const u32 total = (u32)__shfl((int)pre, 63);
    u32 base = 0;
    if (lane == 63 && total) base = atomicAdd(ncand, total);
    base = (u32)__shfl((int)base, 63);
    u32 off = base + pre - c;

    #pragma unroll
    for (int m = 0; m < 4; ++m)
        #pragma unroll
        for (int r = 0; r < 4; ++r) {
            const int prow = p0 + wm * 64 + m * 16 + g * 4 + r;
            if (kval(b1[m][r]) <= thrv[m][r]) {
                if (off < CAND_CAP) cand[off] = ((u64)(u32)prow << 32) | b1[m][r];
                else flags[prow] = 0u;
                ++off;
            }
            if (kval(b2[m][r]) <= thrv[m][r]) {
                if (off < CAND_CAP) cand[off] = ((u64)(u32)prow << 32) | b2[m][r];
                else flags[prow] = 0u;
                ++off;
            }
        }
}

// ---------------------------------------------------------------------------
// filter: keep candidates within converged grunmin+DELTA, compact into
// per-pixel slot arrays (slots[p][8], pcnt[p]). >8 passers -> flag pixel.
// ---------------------------------------------------------------------------
__global__ void vq_filter(const u32* __restrict__ grunmin,
                          const u64* __restrict__ cand,
                          const u32* __restrict__ ncand,
                          u32* __restrict__ pcnt, u32* __restrict__ slots,
                          u32* __restrict__ flags)
{
    const u32 nc = min(*ncand, CAND_CAP);
    for (u32 i = blockIdx.x * 256 + threadIdx.x; i < nc; i += gridDim.x * 256) {
        const u64 e = cand[i];
        const int p = (int)(e >> 32);
        const u32 pk = (u32)e;
        if (kval(pk) > kval(grunmin[p]) + DELTA) continue;
        const u32 pos = atomicAdd(&pcnt[p], 1u);
        if (pos < 8u) slots[p * 8 + pos] = pk & 8191u;
        else flags[p] = 0u;
    }
}

// ---------------------------------------------------------------------------
// exact: one wg per 16 consecutive pixels.
//  pcnt==1  -> winner direct (no z traffic).
//  pcnt 2..8 -> stage z block [16][260] in LDS coalesced; one wave per
//               candidate does the exact fp32 dot (z LDS, cb L2).
//  flagged  -> full-scan fallback (never in practice).
// ---------------------------------------------------------------------------
__global__ __launch_bounds__(256) void vq_exact(
    const float* __restrict__ z, const float* __restrict__ cb,
    const float* __restrict__ e2, const u32* __restrict__ pcnt,
    const u32* __restrict__ slots, const u32* __restrict__ flags,
    u64* __restrict__ final_)
{
    __shared__ float zb[16][260];
    __shared__ u32 work[128];      // (pix<<16) | n
    __shared__ int nwork;

    const int tid = threadIdx.x;
    const int g0  = blockIdx.x * 16;
    const int bb  = g0 >> 10, hw0 = g0 & 1023;

    if (tid == 0) nwork = 0;
    __syncthreads();
    if (tid < 16) {
        const int p = g0 + tid;
        if (flags[p] != 0u) {                 // not overflow-flagged
            const u32 c = pcnt[p];
            if (c == 1u) {
                final_[p] = (u64)slots[p * 8];     // key 0 -> wins, no dot needed
            } else if (c >= 2u) {              // c <= 8 guaranteed (else flagged)
                const int base = atomicAdd(&nwork, (int)c);
                for (u32 i = 0; i < c; ++i)
                    work[base + i] = ((u32)tid << 16) | slots[p * 8 + i];
            }
        }
    }
    __syncthreads();
    const int nw = nwork;
    if (nw > 0) {
        #pragma unroll
        for (int i = 0; i < 16; ++i) {
            const int idx = i * 256 + tid;
            const int c = idx >> 4, pix = idx & 15;
            zb[pix][c] = z[(size_t)bb * BCHW + (size_t)c * HW + hw0 + pix];
        }
        __syncthreads();
        const int wv = tid >> 6, lane = tid & 63;
        for (int wi = wv; wi < nw; wi += 4) {
            const u32 e = work[wi];
            const int pix = (int)(e >> 16), n = (int)(e & 0xFFFFu);
            const f32x4 zv = *(const f32x4*)&zb[pix][lane * 4];
            const f32x4 ev = *(const f32x4*)(cb + (size_t)n * KD + lane * 4);
            float part = zv[0]*ev[0] + zv[1]*ev[1] + zv[2]*ev[2] + zv[3]*ev[3];
            #pragma unroll
            for (int m = 1; m < 64; m <<= 1) part += __shfl_xor(part, m);
            if (lane == 0) {
                const float s = 0.5f * e2[n] - part;
                atomicMin(&final_[g0 + pix], ((u64)fkey(s) << 32) | (u32)n);
            }
        }
    }

    // overflow fallback: exact scan of all codes for flagged pixels
    const int gwv = (blockIdx.x * 256 + tid) >> 6;
    const int lane = tid & 63;
    const int nwv = gridDim.x * 4;
    for (int p = gwv; p < NPIX; p += nwv) {
        if (flags[p] != 0u) continue;
        const int b2_ = p >> 10, hw = p & 1023;
        const float* zp = z + b2_ * BCHW + hw;
        float bd = FLT_MAX; int bn = 0;
        for (int n = lane; n < NE; n += 64) {
            float s = 0.f;
            for (int k = 0; k < KD; ++k) s += zp[k * HW] * cb[(size_t)n * KD + k];
            s = 0.5f * e2[n] - s;
            if (s < bd) { bd = s; bn = n; }
        }
        #pragma unroll
        for (int msk = 1; msk < 64; msk <<= 1) {
            const float od = __shfl_xor(bd, msk);
            const int   on = __shfl_xor(bn, msk);
            if (od < bd || (od == bd && on < bn)) { bd = od; bn = on; }
        }
        if (lane == 0) atomicMin(&final_[p], ((u64)fkey(bd) << 32) | (u32)bn);
    }
}

// ---------------------------------------------------------------------------
// Output kernel, tile-transposed.
// ---------------------------------------------------------------------------
__global__ __launch_bounds__(256) void vq_out_kernel(
    const float* __restrict__ z, const float* __restrict__ cb,
    const u64* __restrict__ final_, float* __restrict__ out,
    float* __restrict__ idxf, float* __restrict__ loss)
{
    __shared__ float zq[32][257];
    __shared__ int   nidx[32];

    const int tid = threadIdx.x;
    const int p0  = blockIdx.x * 32;
    const int bb  = p0 >> 10;
    const int hw0 = p0 & 1023;

    if (tid < 32) {
        const int n = (int)((u32)final_[p0 + tid] & 8191u);
        nidx[tid] = n;
        idxf[p0 + tid] = (float)n;
    }
    __syncthreads();

    {
        const int r = tid >> 3, i = tid & 7;
        const float* src = cb + (size_t)nidx[r] * KD;
        #pragma unroll
        for (int j = 0; j < 8; ++j) {
            const int col = i * 4 + j * 32;
            const f32x4 v = *(const f32x4*)(src + col);
            zq[r][col + 0] = v[0]; zq[r][col + 1] = v[1];
            zq[r][col + 2] = v[2]; zq[r][col + 3] = v[3];
        }
    }
    __syncthreads();

    const int p4 = (tid & 7) * 4;
    const int cg = tid >> 3;
    float ls = 0.f;
    #pragma unroll
    for (int ii = 0; ii < 8; ++ii) {
        const int c = cg + 32 * ii;
        const size_t e = (size_t)bb * BCHW + (size_t)c * HW + hw0 + p4;
        const f32x4 zv = *(const f32x4*)(z + e);
        f32x4 v;
        v[0] = zq[p4 + 0][c]; v[1] = zq[p4 + 1][c];
        v[2] = zq[p4 + 2][c]; v[3] = zq[p4 + 3][c];
        *(f32x4*)(out + e) = v;
        const float d0 = v[0] - zv[0], d1 = v[1] - zv[1];
        const float d2 = v[2] - zv[2], d3 = v[3] - zv[3];
        ls += d0 * d0 + d1 * d1 + d2 * d2 + d3 * d3;
    }
    #pragma unroll
    for (int m = 1; m < 64; m <<= 1) ls += __shfl_xor(ls, m);
    if ((tid & 63) == 0) atomicAdd(loss, ls * (1.25f / 4194304.f));
}

// ---------------------------------------------------------------------------
extern "C" void kernel_launch(void* const* d_in, const int* in_sizes, int n_in,
                              void* d_out, int out_size, void* d_ws, size_t ws_size,
                              hipStream_t stream) {
    const float* z  = (const float*)d_in[0];
    const float* cb = (const float*)d_in[1];
    float* out  = (float*)d_out;
    float* idxf = out + 4194304;
    float* loss = out + 4210688;
    // scratch inside the z_q region of d_out (fully overwritten at the end):
    char* ob = (char*)d_out;
    short* zh    = (short*)ob;                    // [0 .. 8MB)   bf16 z [p][k]
    short* eh    = (short*)(ob + 8388608);        // [8 .. 12MB)  bf16 codebook
    u64*   cand  = (u64*)(ob + 12582912);         // [12 .. 16MB) 524288 slots

    char* ws = (char*)d_ws;
    u32*   grunmin = (u32*)ws;               // 64 KB  @ 0
    u32*   flags   = (u32*)(ws + 65536);     // 64 KB
    u64*   final_  = (u64*)(ws + 131072);    // 128 KB
    float* e2      = (float*)(ws + 262144);  // 32 KB
    u32*   ncand   = (u32*)(ws + 294912);    // 256 B slot
    u32*   pcnt    = (u32*)(ws + 295168);    // 64 KB
    u32*   slots   = (u32*)(ws + 360704);    // 512 KB   (total ws use ~873 KB)

    hipMemsetAsync(ws, 0xFF, 262144, stream);       // grunmin+flags+final_
    hipMemsetAsync(ncand, 0, 4, stream);
    hipMemsetAsync(pcnt, 0, 65536, stream);
    hipMemsetAsync(loss, 0, 4, stream);

    vq_prep<<<2048, 256, 0, stream>>>(cb, eh, e2);
    vq_zh<<<dim3(16, 4, 16), 256, 0, stream>>>(z, zh);
    vq_gemm<<<dim3(NE / (NT * 128), NPIX / 128), 256, 0, stream>>>(
        zh, eh, grunmin, flags, cand, ncand);
    vq_filter<<<256, 256, 0, stream>>>(grunmin, cand, ncand, pcnt, slots, flags);
    vq_exact<<<NPIX / 16, 256, 0, stream>>>(z, cb, e2, pcnt, slots, flags, final_);
    vq_out_kernel<<<NPIX / 32, 256, 0, stream>>>(z, cb, final_, out, idxf, loss);
}

// Round 10
// 469.319 us; speedup vs baseline: 22.3753x; 3.5693x over previous
//
#include <hip/hip_runtime.h>
#include <float.h>

#define NPIX 16384    // B*H*W pixels
#define NE   8192     // codebook entries
#define KD   256      // channels
#define HW   1024
#define BCHW 262144
#define NT   8        // N-tiles (128 codes) per wg -> wg spans 1024 codes
#define CAND_CAP 524288u
#define DELTA 2.5e-4f // emission/filter window: bf16 err + 2x key quant + e2 spread
#define KMASK 0xFFFFE000u
#define SLOT_CAP 16u

typedef __attribute__((ext_vector_type(8))) short short8;
typedef __attribute__((ext_vector_type(4))) short short4v;
typedef __attribute__((ext_vector_type(4))) float f32x4;
typedef unsigned long long u64;
typedef unsigned int u32;
typedef unsigned short u16;

__device__ __forceinline__ u32 fkey(float f) {
    u32 u = __float_as_uint(f);
    return u ^ ((u >> 31) ? 0xFFFFFFFFu : 0x80000000u);
}
__device__ __forceinline__ short bf16rne(float f) {
    u32 u = __float_as_uint(f);
    u += 0x7FFFu + ((u >> 16) & 1u);
    return (short)(u >> 16);
}
__device__ __forceinline__ float kval(u32 pk) {   // packed key -> quantized value
    return __uint_as_float(pk & KMASK);
}

#define GLDS(gp, lp) __builtin_amdgcn_global_load_lds( \
    (const __attribute__((address_space(1))) void*)(gp), \
    (__attribute__((address_space(3))) void*)(lp), 16, 0, 0)

// ---------------------------------------------------------------------------
// prep: codebook -> bf16 AND e2[n] = ||e_n||^2. One wave per row.
// ---------------------------------------------------------------------------
__global__ void vq_prep(const float* __restrict__ cb, short* __restrict__ eh,
                        float* __restrict__ e2) {
    const int row  = (blockIdx.x * 256 + threadIdx.x) >> 6;
    const int lane = threadIdx.x & 63;
    const f32x4 v = *(const f32x4*)(cb + (size_t)row * KD + lane * 4);
    short4v h;
    h[0] = bf16rne(v[0]); h[1] = bf16rne(v[1]);
    h[2] = bf16rne(v[2]); h[3] = bf16rne(v[3]);
    *(short4v*)(eh + (size_t)row * KD + lane * 4) = h;
    float s = v[0]*v[0] + v[1]*v[1] + v[2]*v[2] + v[3]*v[3];
    #pragma unroll
    for (int m = 1; m < 64; m <<= 1) s += __shfl_xor(s, m);
    if (lane == 0) e2[row] = s;
}

// ---------------------------------------------------------------------------
// z [b][k][hw] fp32 -> zh [p][k] bf16 (transpose via LDS)
// ---------------------------------------------------------------------------
__global__ void vq_zh(const float* __restrict__ z, short* __restrict__ zh) {
    __shared__ float ts[64][65];
    const int b   = blockIdx.z;
    const int k0  = blockIdx.y * 64;
    const int hw0 = blockIdx.x * 64;
    const int tid = threadIdx.x;
    const int pl  = tid & 63, kk = tid >> 6;
    #pragma unroll
    for (int i = 0; i < 16; ++i) {
        const int k = kk + 4 * i;
        ts[k][pl] = z[b * BCHW + (k0 + k) * HW + hw0 + pl];
    }
    __syncthreads();
    const int tx = tid & 15, ty = tid >> 4;
    #pragma unroll
    for (int j = 0; j < 4; ++j) {
        const int p = ty + 16 * j;
        short4v v;
        #pragma unroll
        for (int q = 0; q < 4; ++q) v[q] = bf16rne(ts[tx * 4 + q][p]);
        *(short4v*)(zh + (size_t)(b * HW + hw0 + p) * KD + k0 + tx * 4) = v;
    }
}

// ---------------------------------------------------------------------------
// Single-pass fused GEMM + argmin + candidate collection (unchanged from R9).
// ---------------------------------------------------------------------------
__global__ __launch_bounds__(256) void vq_gemm(
    const short* __restrict__ zh, const short* __restrict__ eh,
    u32* __restrict__ grunmin, u32* __restrict__ flags,
    u64* __restrict__ cand, u32* __restrict__ ncand)
{
    __shared__ short As[2][4096];   // [buf][128 rows x 32 k]
    __shared__ short Bs[2][4096];

    const int tid  = threadIdx.x;
    const int lane = tid & 63;
    const int w    = tid >> 6;
    const int wm   = w >> 1, wn = w & 1;
    const int p0   = blockIdx.y * 128;
    const int nb0  = blockIdx.x * (NT * 128);

    const int sr = lane >> 2;
    const int ss = (lane & 3) ^ ((sr >> 1) & 3);
    const int q   = lane >> 4;
    const int rsw = ((lane & 15) >> 1) & 3;

    u32 b1[4][4], b2[4][4];
    #pragma unroll
    for (int m = 0; m < 4; ++m)
        #pragma unroll
        for (int r = 0; r < 4; ++r) { b1[m][r] = 0xFFFFFFFFu; b2[m][r] = 0xFFFFFFFFu; }

    #define STAGE(nt_, t_, buf_) do {                                          \
        const int k0_ = (t_) * 32;                                             \
        const int n0_ = nb0 + (nt_) * 128;                                     \
        _Pragma("unroll")                                                      \
        for (int i_ = 0; i_ < 2; ++i_) {                                       \
            const int rb_ = w * 32 + i_ * 16;                                  \
            GLDS(zh + (size_t)(p0 + rb_ + sr) * KD + k0_ + ss * 8,             \
                 &As[buf_][rb_ * 32]);                                         \
            GLDS(eh + (size_t)(n0_ + rb_ + sr) * KD + k0_ + ss * 8,            \
                 &Bs[buf_][rb_ * 32]);                                         \
        }                                                                      \
    } while (0)

    f32x4 acc[4][4];

    STAGE(0, 0, 0);
    __syncthreads();

    #pragma unroll 1
    for (int nt = 0; nt < NT; ++nt) {
        #pragma unroll
        for (int m = 0; m < 4; ++m)
            #pragma unroll
            for (int nf = 0; nf < 4; ++nf)
                acc[m][nf] = (f32x4){0.f, 0.f, 0.f, 0.f};

        #pragma unroll
        for (int t = 0; t < 8; ++t) {
            const int buf = t & 1;
            if (t < 7)            { STAGE(nt, t + 1, buf ^ 1); }
            else if (nt + 1 < NT) { STAGE(nt + 1, 0, buf ^ 1); }

            short8 af[4], bfv[4];
            #pragma unroll
            for (int m = 0; m < 4; ++m) {
                const int row = wm * 64 + m * 16 + (lane & 15);
                af[m] = *(const short8*)&As[buf][row * 32 + ((q ^ rsw) * 8)];
            }
            #pragma unroll
            for (int nf = 0; nf < 4; ++nf) {
                const int row = wn * 64 + nf * 16 + (lane & 15);
                bfv[nf] = *(const short8*)&Bs[buf][row * 32 + ((q ^ rsw) * 8)];
            }
            #pragma unroll
            for (int m = 0; m < 4; ++m)
                #pragma unroll
                for (int nf = 0; nf < 4; ++nf)
                    acc[m][nf] = __builtin_amdgcn_mfma_f32_16x16x32_bf16(
                        af[m], bfv[nf], acc[m][nf], 0, 0, 0);

            if (t == 7) {
                const u32 nbase = (u32)(nb0 + nt * 128 + wn * 64 + (lane & 15));
                #pragma unroll
                for (int m = 0; m < 4; ++m) {
                    #pragma unroll
                    for (int r = 0; r < 4; ++r) {
                        u32 pk0 = (__float_as_uint(0.0625f - acc[m][0][r]) & KMASK) | (nbase);
                        u32 pk1 = (__float_as_uint(0.0625f - acc[m][1][r]) & KMASK) | (nbase + 16u);
                        u32 pk2 = (__float_as_uint(0.0625f - acc[m][2][r]) & KMASK) | (nbase + 32u);
                        u32 pk3 = (__float_as_uint(0.0625f - acc[m][3][r]) & KMASK) | (nbase + 48u);
                        const u32 lo01 = min(pk0, pk1), hi01 = max(pk0, pk1);
                        const u32 lo23 = min(pk2, pk3), hi23 = max(pk2, pk3);
                        const u32 m1 = min(lo01, lo23);
                        const u32 m2 = min(max(lo01, lo23), min(hi01, hi23));
                        const u32 nb1 = min(b1[m][r], m1);
                        const u32 nb2 = min(max(b1[m][r], m1), min(b2[m][r], m2));
                        b1[m][r] = nb1; b2[m][r] = nb2;
                    }
                }
            }
            __syncthreads();
        }
    }
    #undef STAGE

    // ---- wg-end: per-pixel local bound via 16-lane min-fold of b1 ----
    u32 bmin[4][4];
    #pragma unroll
    for (int m = 0; m < 4; ++m)
        #pragma unroll
        for (int r = 0; r < 4; ++r) {
            u32 v = b1[m][r];
            #pragma unroll
            for (int msk = 1; msk < 16; msk <<= 1)
                v = min(v, (u32)__shfl_xor((int)v, msk));
            bmin[m][r] = v;
        }

    // publish per-pixel slice-min (distributed atomics, 16/wave)
    const int g = lane >> 4;
    if ((lane & 15) == 0) {
        #pragma unroll
        for (int m = 0; m < 4; ++m)
            #pragma unroll
            for (int r = 0; r < 4; ++r)
                atomicMin(&grunmin[p0 + wm * 64 + m * 16 + g * 4 + r], bmin[m][r]);
    }

    // read back the (partially converged) global bound; >= final grunmin,
    // so emission stays a superset of the final filter set.
    float thrv[4][4];
    #pragma unroll
    for (int m = 0; m < 4; ++m)
        #pragma unroll
        for (int r = 0; r < 4; ++r) {
            const int prow = p0 + wm * 64 + m * 16 + g * 4 + r;
            const u32 gb = grunmin[prow];
            thrv[m][r] = kval(min(bmin[m][r], gb)) + DELTA;
        }

    // count emissions
    u32 c = 0;
    #pragma unroll
    for (int m = 0; m < 4; ++m)
        #pragma unroll
        for (int r = 0; r < 4; ++r) {
            c += (kval(b1[m][r]) <= thrv[m][r]) ? 1u : 0u;
            c += (kval(b2[m][r]) <= thrv[m][r]) ? 1u : 0u;
        }

    // wave prefix scan + single ncand atomic per wave
    u32 pre = c;
    #pragma unroll
    for (int d = 1; d < 64; d <<= 1) {
        const u32 t = (u32)__shfl_up((int)pre, d);
        if (lane >= d) pre += t;
    }
    const u32 total = (u32)__shfl((int)pre, 63);
    u32 base = 0;
    if (lane == 63 && total) base = atomicAdd(ncand, total);
    base = (u32)__shfl((int)base, 63);
    u32 off = base + pre - c;

    #pragma unroll
    for (int m = 0; m < 4; ++m)
        #pragma unroll
        for (int r = 0; r < 4; ++r) {
            const int prow = p0 + wm * 64 + m * 16 + g * 4 + r;
            if (kval(b1[m][r]) <= thrv[m][r]) {
                if (off < CAND_CAP) cand[off] = ((u64)(u32)prow << 32) | b1[m][r];
                else flags[prow] = 0u;
                ++off;
            }
            if (kval(b2[m][r]) <= thrv[m][r]) {
                if (off < CAND_CAP) cand[off] = ((u64)(u32)prow << 32) | b2[m][r];
                else flags[prow] = 0u;
                ++off;
            }
        }
}

// ---------------------------------------------------------------------------
// filter: keep candidates within converged grunmin+DELTA, compact into
// per-pixel slot arrays (u16 slots[p][16], pcnt[p]). >16 passers -> flag.
// ---------------------------------------------------------------------------
__global__ void vq_filter(const u32* __restrict__ grunmin,
                          const u64* __restrict__ cand,
                          const u32* __restrict__ ncand,
                          u32* __restrict__ pcnt, u16* __restrict__ slots,
                          u32* __restrict__ flags)
{
    const u32 nc = min(*ncand, CAND_CAP);
    for (u32 i = blockIdx.x * 256 + threadIdx.x; i < nc; i += gridDim.x * 256) {
        const u64 e = cand[i];
        const int p = (int)(e >> 32);
        const u32 pk = (u32)e;
        if (kval(pk) > kval(grunmin[p]) + DELTA) continue;
        const u32 pos = atomicAdd(&pcnt[p], 1u);
        if (pos < SLOT_CAP) slots[p * 16 + pos] = (u16)(pk & 8191u);
        else flags[p] = 0u;
    }
}

// ---------------------------------------------------------------------------
// exact: one wg per 16 consecutive pixels.
//  pcnt==1   -> winner direct (no z traffic).
//  pcnt 2..16 -> stage z block [16][260] in LDS coalesced; one wave per
//                candidate does the exact fp32 dot (z LDS, cb L2).
//  flagged   -> full scan of this wg's own flagged pixels, 256-thread
//               parallel over codes with z from LDS (rare; ~30us/pixel).
// ---------------------------------------------------------------------------
__global__ __launch_bounds__(256) void vq_exact(
    const float* __restrict__ z, const float* __restrict__ cb,
    const float* __restrict__ e2, const u32* __restrict__ pcnt,
    const u16* __restrict__ slots, const u32* __restrict__ flags,
    u64* __restrict__ final_)
{
    __shared__ float zb[16][260];
    __shared__ u32 work[256];      // (pix<<16) | n
    __shared__ int nwork;
    __shared__ int nbad;
    __shared__ u32 badl[16];

    const int tid = threadIdx.x;
    const int g0  = blockIdx.x * 16;
    const int bb  = g0 >> 10, hw0 = g0 & 1023;

    if (tid == 0) { nwork = 0; nbad = 0; }
    __syncthreads();
    if (tid < 16) {
        const int p = g0 + tid;
        if (flags[p] != 0u) {                 // not overflow-flagged
            const u32 c = pcnt[p];
            if (c == 1u) {
                final_[p] = (u64)slots[p * 16];    // key 0 -> wins, no dot needed
            } else if (c >= 2u) {              // c <= 16 guaranteed (else flagged)
                const int base = atomicAdd(&nwork, (int)c);
                for (u32 i = 0; i < c; ++i)
                    work[base + i] = ((u32)tid << 16) | (u32)slots[p * 16 + i];
            }
        } else {
            badl[atomicAdd(&nbad, 1)] = (u32)tid;
        }
    }
    __syncthreads();
    const int nw = nwork, nb = nbad;
    if (nw > 0 || nb > 0) {
        // stage the 16-pixel z block coalesced (shared by all candidates)
        #pragma unroll
        for (int i = 0; i < 16; ++i) {
            const int idx = i * 256 + tid;
            const int c = idx >> 4, pix = idx & 15;
            zb[pix][c] = z[(size_t)bb * BCHW + (size_t)c * HW + hw0 + pix];
        }
        __syncthreads();
        const int wv = tid >> 6, lane = tid & 63;
        for (int wi = wv; wi < nw; wi += 4) {
            const u32 e = work[wi];
            const int pix = (int)(e >> 16), n = (int)(e & 0xFFFFu);
            const f32x4 zv = *(const f32x4*)&zb[pix][lane * 4];
            const f32x4 ev = *(const f32x4*)(cb + (size_t)n * KD + lane * 4);
            float part = zv[0]*ev[0] + zv[1]*ev[1] + zv[2]*ev[2] + zv[3]*ev[3];
            #pragma unroll
            for (int m = 1; m < 64; m <<= 1) part += __shfl_xor(part, m);
            if (lane == 0) {
                const float s = 0.5f * e2[n] - part;
                atomicMin(&final_[g0 + pix], ((u64)fkey(s) << 32) | (u32)n);
            }
        }
        // fallback: own flagged pixels, all 256 threads split the codes
        for (int bi = 0; bi < nb; ++bi) {
            const int pix = (int)badl[bi];
            float bd = FLT_MAX; int bn = 0;
            for (int n = tid; n < NE; n += 256) {
                const float* er = cb + (size_t)n * KD;
                float s = 0.f;
                for (int k = 0; k < KD; k += 4)
                    s += zb[pix][k]*er[k] + zb[pix][k+1]*er[k+1]
                       + zb[pix][k+2]*er[k+2] + zb[pix][k+3]*er[k+3];
                s = 0.5f * e2[n] - s;
                if (s < bd || (s == bd && n < bn)) { bd = s; bn = n; }
            }
            atomicMin(&final_[g0 + pix], ((u64)fkey(bd) << 32) | (u32)bn);
        }
    }
}

// ---------------------------------------------------------------------------
// Output kernel, tile-transposed.
// ---------------------------------------------------------------------------
__global__ __launch_bounds__(256) void vq_out_kernel(
    const float* __restrict__ z, const float* __restrict__ cb,
    const u64* __restrict__ final_, float* __restrict__ out,
    float* __restrict__ idxf, float* __restrict__ loss)
{
    __shared__ float zq[32][257];
    __shared__ int   nidx[32];

    const int tid = threadIdx.x;
    const int p0  = blockIdx.x * 32;
    const int bb  = p0 >> 10;
    const int hw0 = p0 & 1023;

    if (tid < 32) {
        const int n = (int)((u32)final_[p0 + tid] & 8191u);
        nidx[tid] = n;
        idxf[p0 + tid] = (float)n;
    }
    __syncthreads();

    {
        const int r = tid >> 3, i = tid & 7;
        const float* src = cb + (size_t)nidx[r] * KD;
        #pragma unroll
        for (int j = 0; j < 8; ++j) {
            const int col = i * 4 + j * 32;
            const f32x4 v = *(const f32x4*)(src + col);
            zq[r][col + 0] = v[0]; zq[r][col + 1] = v[1];
            zq[r][col + 2] = v[2]; zq[r][col + 3] = v[3];
        }
    }
    __syncthreads();

    const int p4 = (tid & 7) * 4;
    const int cg = tid >> 3;
    float ls = 0.f;
    #pragma unroll
    for (int ii = 0; ii < 8; ++ii) {
        const int c = cg + 32 * ii;
        const size_t e = (size_t)bb * BCHW + (size_t)c * HW + hw0 + p4;
        const f32x4 zv = *(const f32x4*)(z + e);
        f32x4 v;
        v[0] = zq[p4 + 0][c]; v[1] = zq[p4 + 1][c];
        v[2] = zq[p4 + 2][c]; v[3] = zq[p4 + 3][c];
        *(f32x4*)(out + e) = v;
        const float d0 = v[0] - zv[0], d1 = v[1] - zv[1];
        const float d2 = v[2] - zv[2], d3 = v[3] - zv[3];
        ls += d0 * d0 + d1 * d1 + d2 * d2 + d3 * d3;
    }
    #pragma unroll
    for (int m = 1; m < 64; m <<= 1) ls += __shfl_xor(ls, m);
    if ((tid & 63) == 0) atomicAdd(loss, ls * (1.25f / 4194304.f));
}

// ---------------------------------------------------------------------------
extern "C" void kernel_launch(void* const* d_in, const int* in_sizes, int n_in,
                              void* d_out, int out_size, void* d_ws, size_t ws_size,
                              hipStream_t stream) {
    const float* z  = (const float*)d_in[0];
    const float* cb = (const float*)d_in[1];
    float* out  = (float*)d_out;
    float* idxf = out + 4194304;
    float* loss = out + 4210688;
    // scratch inside the z_q region of d_out (fully overwritten at the end):
    char* ob = (char*)d_out;
    short* zh    = (short*)ob;                    // [0 .. 8MB)   bf16 z [p][k]
    short* eh    = (short*)(ob + 8388608);        // [8 .. 12MB)  bf16 codebook
    u64*   cand  = (u64*)(ob + 12582912);         // [12 .. 16MB) 524288 slots

    char* ws = (char*)d_ws;
    u32*   grunmin = (u32*)ws;               // 64 KB  @ 0
    u32*   flags   = (u32*)(ws + 65536);     // 64 KB
    u64*   final_  = (u64*)(ws + 131072);    // 128 KB
    float* e2      = (float*)(ws + 262144);  // 32 KB
    u32*   ncand   = (u32*)(ws + 294912);    // 256 B slot
    u32*   pcnt    = (u32*)(ws + 295168);    // 64 KB
    u16*   slots   = (u16*)(ws + 360704);    // 512 KB  (total ws use ~873 KB, same as R9)

    hipMemsetAsync(ws, 0xFF, 262144, stream);       // grunmin+flags+final_
    hipMemsetAsync(ncand, 0, 4, stream);
    hipMemsetAsync(pcnt, 0, 65536, stream);
    hipMemsetAsync(loss, 0, 4, stream);

    vq_prep<<<2048, 256, 0, stream>>>(cb, eh, e2);
    vq_zh<<<dim3(16, 4, 16), 256, 0, stream>>>(z, zh);
    vq_gemm<<<dim3(NE / (NT * 128), NPIX / 128), 256, 0, stream>>>(
        zh, eh, grunmin, flags, cand, ncand);
    vq_filter<<<256, 256, 0, stream>>>(grunmin, cand, ncand, pcnt, slots, flags);
    vq_exact<<<NPIX / 16, 256, 0, stream>>>(z, cb, e2, pcnt, slots, flags, final_);
    vq_out_kernel<<<NPIX / 32, 256, 0, stream>>>(z, cb, final_, out, idxf, loss);
}

// Round 14
// 301.541 us; speedup vs baseline: 34.8249x; 1.5564x over previous
//
#include <hip/hip_runtime.h>
#include <float.h>

#define NPIX 16384    // B*H*W pixels
#define NE   8192     // codebook entries
#define KD   256      // channels
#define HW   1024
#define BCHW 262144
#define NT   8        // N-tiles (128 codes) per wg -> wg spans 1024 codes (slice)
#define DELTA 2.5e-4f // rescue window: bf16 err + 2x key quant + margin
#define KMASK 0xFFFFE000u

typedef __attribute__((ext_vector_type(8))) short short8;
typedef __attribute__((ext_vector_type(4))) short short4v;
typedef __attribute__((ext_vector_type(4))) float f32x4;
typedef __attribute__((ext_vector_type(4))) unsigned int u32x4;
typedef unsigned long long u64;
typedef unsigned int u32;

__device__ __forceinline__ u32 fkey(float f) {
    u32 u = __float_as_uint(f);
    return u ^ ((u >> 31) ? 0xFFFFFFFFu : 0x80000000u);
}
__device__ __forceinline__ short bf16rne(float f) {
    u32 u = __float_as_uint(f);
    u += 0x7FFFu + ((u >> 16) & 1u);
    return (short)(u >> 16);
}
__device__ __forceinline__ float kval(u32 pk) {   // packed key -> quantized value
    return __uint_as_float(pk & KMASK);
}

#define GLDS(gp, lp) __builtin_amdgcn_global_load_lds( \
    (const __attribute__((address_space(1))) void*)(gp), \
    (__attribute__((address_space(3))) void*)(lp), 16, 0, 0)

// ---------------------------------------------------------------------------
// prep: codebook -> bf16 AND e2[n] = ||e_n||^2. One wave per row.
// ---------------------------------------------------------------------------
__global__ void vq_prep(const float* __restrict__ cb, short* __restrict__ eh,
                        float* __restrict__ e2) {
    const int row  = (blockIdx.x * 256 + threadIdx.x) >> 6;
    const int lane = threadIdx.x & 63;
    const f32x4 v = *(const f32x4*)(cb + (size_t)row * KD + lane * 4);
    short4v h;
    h[0] = bf16rne(v[0]); h[1] = bf16rne(v[1]);
    h[2] = bf16rne(v[2]); h[3] = bf16rne(v[3]);
    *(short4v*)(eh + (size_t)row * KD + lane * 4) = h;
    float s = v[0]*v[0] + v[1]*v[1] + v[2]*v[2] + v[3]*v[3];
    #pragma unroll
    for (int m = 1; m < 64; m <<= 1) s += __shfl_xor(s, m);
    if (lane == 0) e2[row] = s;
}

// ---------------------------------------------------------------------------
// z [b][k][hw] fp32 -> zh [p][k] bf16 (transpose via LDS)
// ---------------------------------------------------------------------------
__global__ void vq_zh(const float* __restrict__ z, short* __restrict__ zh) {
    __shared__ float ts[64][65];
    const int b   = blockIdx.z;
    const int k0  = blockIdx.y * 64;
    const int hw0 = blockIdx.x * 64;
    const int tid = threadIdx.x;
    const int pl  = tid & 63, kk = tid >> 6;
    #pragma unroll
    for (int i = 0; i < 16; ++i) {
        const int k = kk + 4 * i;
        ts[k][pl] = z[b * BCHW + (k0 + k) * HW + hw0 + pl];
    }
    __syncthreads();
    const int tx = tid & 15, ty = tid >> 4;
    #pragma unroll
    for (int j = 0; j < 4; ++j) {
        const int p = ty + 16 * j;
        short4v v;
        #pragma unroll
        for (int q = 0; q < 4; ++q) v[q] = bf16rne(ts[tx * 4 + q][p]);
        *(short4v*)(zh + (size_t)(b * HW + hw0 + p) * KD + k0 + tx * 4) = v;
    }
}

// ---------------------------------------------------------------------------
// Fused GEMM + per-(pixel, HALF-slice) top-4 tracking.
// Each (prow, hs=blockIdx.x*2+wn) has exactly ONE writer wave (race fixed):
// wn selects the 64-of-128 code columns a wave tracks, so its top-4 union
// is stored at its own hs index. Keys: pk = (bits(0.0625-dot)&~0x1FFF)|n.
// ---------------------------------------------------------------------------
__global__ __launch_bounds__(256) void vq_gemm(
    const short* __restrict__ zh, const short* __restrict__ eh,
    u32* __restrict__ best4)
{
    __shared__ short As[2][4096];   // [buf][128 rows x 32 k]
    __shared__ short Bs[2][4096];

    const int tid  = threadIdx.x;
    const int lane = tid & 63;
    const int w    = tid >> 6;
    const int wm   = w >> 1, wn = w & 1;
    const int p0   = blockIdx.y * 128;
    const int nb0  = blockIdx.x * (NT * 128);

    const int sr = lane >> 2;
    const int ss = (lane & 3) ^ ((sr >> 1) & 3);
    const int q   = lane >> 4;
    const int rsw = ((lane & 15) >> 1) & 3;

    u32 b1[4][4], b2[4][4];
    #pragma unroll
    for (int m = 0; m < 4; ++m)
        #pragma unroll
        for (int r = 0; r < 4; ++r) { b1[m][r] = 0xFFFFFFFFu; b2[m][r] = 0xFFFFFFFFu; }

    #define STAGE(nt_, t_, buf_) do {                                          \
        const int k0_ = (t_) * 32;                                             \
        const int n0_ = nb0 + (nt_) * 128;                                     \
        _Pragma("unroll")                                                      \
        for (int i_ = 0; i_ < 2; ++i_) {                                       \
            const int rb_ = w * 32 + i_ * 16;                                  \
            GLDS(zh + (size_t)(p0 + rb_ + sr) * KD + k0_ + ss * 8,             \
                 &As[buf_][rb_ * 32]);                                         \
            GLDS(eh + (size_t)(n0_ + rb_ + sr) * KD + k0_ + ss * 8,            \
                 &Bs[buf_][rb_ * 32]);                                         \
        }                                                                      \
    } while (0)

    f32x4 acc[4][4];

    STAGE(0, 0, 0);
    __syncthreads();

    #pragma unroll 1
    for (int nt = 0; nt < NT; ++nt) {
        #pragma unroll
        for (int m = 0; m < 4; ++m)
            #pragma unroll
            for (int nf = 0; nf < 4; ++nf)
                acc[m][nf] = (f32x4){0.f, 0.f, 0.f, 0.f};

        #pragma unroll
        for (int t = 0; t < 8; ++t) {
            const int buf = t & 1;
            if (t < 7)            { STAGE(nt, t + 1, buf ^ 1); }
            else if (nt + 1 < NT) { STAGE(nt + 1, 0, buf ^ 1); }

            short8 af[4], bfv[4];
            #pragma unroll
            for (int m = 0; m < 4; ++m) {
                const int row = wm * 64 + m * 16 + (lane & 15);
                af[m] = *(const short8*)&As[buf][row * 32 + ((q ^ rsw) * 8)];
            }
            #pragma unroll
            for (int nf = 0; nf < 4; ++nf) {
                const int row = wn * 64 + nf * 16 + (lane & 15);
                bfv[nf] = *(const short8*)&Bs[buf][row * 32 + ((q ^ rsw) * 8)];
            }
            #pragma unroll
            for (int m = 0; m < 4; ++m)
                #pragma unroll
                for (int nf = 0; nf < 4; ++nf)
                    acc[m][nf] = __builtin_amdgcn_mfma_f32_16x16x32_bf16(
                        af[m], bfv[nf], acc[m][nf], 0, 0, 0);

            if (t == 7) {
                // ---- register-only best-2 merge (no shfl, no globals) ----
                const u32 nbase = (u32)(nb0 + nt * 128 + wn * 64 + (lane & 15));
                #pragma unroll
                for (int m = 0; m < 4; ++m) {
                    #pragma unroll
                    for (int r = 0; r < 4; ++r) {
                        u32 pk0 = (__float_as_uint(0.0625f - acc[m][0][r]) & KMASK) | (nbase);
                        u32 pk1 = (__float_as_uint(0.0625f - acc[m][1][r]) & KMASK) | (nbase + 16u);
                        u32 pk2 = (__float_as_uint(0.0625f - acc[m][2][r]) & KMASK) | (nbase + 32u);
                        u32 pk3 = (__float_as_uint(0.0625f - acc[m][3][r]) & KMASK) | (nbase + 48u);
                        const u32 lo01 = min(pk0, pk1), hi01 = max(pk0, pk1);
                        const u32 lo23 = min(pk2, pk3), hi23 = max(pk2, pk3);
                        const u32 m1 = min(lo01, lo23);
                        const u32 m2 = min(max(lo01, lo23), min(hi01, hi23));
                        const u32 nb1 = min(b1[m][r], m1);
                        const u32 nb2 = min(max(b1[m][r], m1), min(b2[m][r], m2));
                        b1[m][r] = nb1; b2[m][r] = nb2;
                    }
                }
            }
            __syncthreads();
        }
    }
    #undef STAGE

    // ---- wg-end: top-4 of this wave's 32-key lane-union per pixel ----
    // (ascending; unique keys -> exactly one lane consumes per round)
    const int g = lane >> 4;
    const int hs = blockIdx.x * 2 + wn;          // half-slice: single writer
    #pragma unroll
    for (int m = 0; m < 4; ++m) {
        #pragma unroll
        for (int r = 0; r < 4; ++r) {
            u32 a = b1[m][r], b = b2[m][r];
            u32 o[4];
            #pragma unroll
            for (int j = 0; j < 4; ++j) {
                u32 mm = a;
                #pragma unroll
                for (int msk = 1; msk < 16; msk <<= 1)
                    mm = min(mm, (u32)__shfl_xor((int)mm, msk));
                o[j] = mm;
                if (a == mm) { a = b; b = 0xFFFFFFFFu; }
            }
            if ((lane & 15) == 0) {
                const int prow = p0 + wm * 64 + m * 16 + g * 4 + r;
                u32x4 ov; ov[0] = o[0]; ov[1] = o[1]; ov[2] = o[2]; ov[3] = o[3];
                *(u32x4*)&best4[((size_t)prow * 16 + hs) * 4] = ov;
            }
        }
    }
}

// ---------------------------------------------------------------------------
// exact: one wg per 16 consecutive pixels. Per pixel: 64 stored keys
// (16 half-slices x top-4 ascending), window = min+DELTA.
//  - half-slice 4th key inside window -> possible in-window truncation ->
//    exact fp32 scan of that 512-code half-slice.
//  - 1 passer & no suspect -> direct winner (no z traffic).
//  - else exact fp32 dots for passers (z staged in LDS coalesced).
// ---------------------------------------------------------------------------
__global__ __launch_bounds__(256) void vq_exact(
    const float* __restrict__ z, const float* __restrict__ cb,
    const float* __restrict__ e2, const u32* __restrict__ best4,
    u64* __restrict__ final_)
{
    __shared__ float zb[16][260];
    __shared__ u32 work[1024];     // (pix<<16) | n
    __shared__ u32 smask[16];      // per-pixel bitmask of half-slices to scan
    __shared__ int nwork;
    __shared__ int nscan;

    const int tid = threadIdx.x;
    const int g0  = blockIdx.x * 16;
    const int bb  = g0 >> 10, hw0 = g0 & 1023;

    if (tid == 0) { nwork = 0; nscan = 0; }
    if (tid < 16) smask[tid] = 0u;
    __syncthreads();
    if (tid < 16) {
        const int p = g0 + tid;
        const u32* src = &best4[(size_t)p * 64];
        u32 mn = 0xFFFFFFFFu;
        for (int i = 0; i < 64; ++i) mn = min(mn, src[i]);   // pass 1 (L1)
        const float thr = kval(mn) + DELTA;
        int cnt = 0;
        u32 sm = 0;
        for (int hsx = 0; hsx < 16; ++hsx) {                 // pass 2 (L1)
            int c4 = 0;
            #pragma unroll
            for (int j = 0; j < 4; ++j)
                c4 += (kval(src[hsx * 4 + j]) <= thr) ? 1 : 0;
            cnt += c4;
            if (c4 == 4) sm |= (1u << hsx);                  // 4th key in window
        }
        if (cnt == 1 && sm == 0u) {
            final_[p] = (u64)(mn & 8191u);       // sole candidate wins directly
        } else {
            const int base = atomicAdd(&nwork, cnt);
            int k = 0;
            for (int i = 0; i < 64; ++i)                     // pass 3 (L1)
                if (kval(src[i]) <= thr)
                    work[base + (k++)] = ((u32)tid << 16) | (src[i] & 8191u);
            if (sm) { smask[tid] = sm; atomicAdd(&nscan, 1); }
        }
    }
    __syncthreads();
    const int nw = nwork, ns = nscan;
    if (nw == 0 && ns == 0) return;

    // stage the 16-pixel z block coalesced (shared by all candidates)
    #pragma unroll
    for (int i = 0; i < 16; ++i) {
        const int idx = i * 256 + tid;
        const int c = idx >> 4, pix = idx & 15;
        zb[pix][c] = z[(size_t)bb * BCHW + (size_t)c * HW + hw0 + pix];
    }
    __syncthreads();
    const int wv = tid >> 6, lane = tid & 63;

    // exact rescore of stored passers: one wave per candidate
    for (int wi = wv; wi < nw; wi += 4) {
        const u32 e = work[wi];
        const int pix = (int)(e >> 16), n = (int)(e & 0xFFFFu);
        const f32x4 zv = *(const f32x4*)&zb[pix][lane * 4];
        const f32x4 ev = *(const f32x4*)(cb + (size_t)n * KD + lane * 4);
        float part = zv[0]*ev[0] + zv[1]*ev[1] + zv[2]*ev[2] + zv[3]*ev[3];
        #pragma unroll
        for (int m = 1; m < 64; m <<= 1) part += __shfl_xor(part, m);
        if (lane == 0) {
            const float s = 0.5f * e2[n] - part;
            atomicMin(&final_[g0 + pix], ((u64)fkey(s) << 32) | (u32)n);
        }
    }

    // exact scan of truncation-suspect half-slices (rare; ~4us each)
    if (ns) {
        for (int pix = 0; pix < 16; ++pix) {
            u32 msk = smask[pix];
            while (msk) {
                const int hsx = __ffs(msk) - 1;
                msk &= msk - 1u;
                const f32x4 zv = *(const f32x4*)&zb[pix][lane * 4];
                for (int ci = wv; ci < 512; ci += 4) {
                    const int n = (hsx >> 1) * 1024 + (ci >> 6) * 128
                                + (hsx & 1) * 64 + (ci & 63);
                    const f32x4 ev = *(const f32x4*)(cb + (size_t)n * KD + lane * 4);
                    float part = zv[0]*ev[0] + zv[1]*ev[1] + zv[2]*ev[2] + zv[3]*ev[3];
                    #pragma unroll
                    for (int m = 1; m < 64; m <<= 1) part += __shfl_xor(part, m);
                    if (lane == 0) {
                        const float sc = 0.5f * e2[n] - part;
                        atomicMin(&final_[g0 + pix], ((u64)fkey(sc) << 32) | (u32)n);
                    }
                }
            }
        }
    }
}

// ---------------------------------------------------------------------------
// Output kernel, tile-transposed.
// ---------------------------------------------------------------------------
__global__ __launch_bounds__(256) void vq_out_kernel(
    const float* __restrict__ z, const float* __restrict__ cb,
    const u64* __restrict__ final_, float* __restrict__ out,
    float* __restrict__ idxf, float* __restrict__ loss)
{
    __shared__ float zq[32][257];
    __shared__ int   nidx[32];

    const int tid = threadIdx.x;
    const int p0  = blockIdx.x * 32;
    const int bb  = p0 >> 10;
    const int hw0 = p0 & 1023;

    if (tid < 32) {
        const int n = (int)((u32)final_[p0 + tid] & 8191u);
        nidx[tid] = n;
        idxf[p0 + tid] = (float)n;
    }
    __syncthreads();

    {
        const int r = tid >> 3, i = tid & 7;
        const float* src = cb + (size_t)nidx[r] * KD;
        #pragma unroll
        for (int j = 0; j < 8; ++j) {
            const int col = i * 4 + j * 32;
            const f32x4 v = *(const f32x4*)(src + col);
            zq[r][col + 0] = v[0]; zq[r][col + 1] = v[1];
            zq[r][col + 2] = v[2]; zq[r][col + 3] = v[3];
        }
    }
    __syncthreads();

    const int p4 = (tid & 7) * 4;
    const int cg = tid >> 3;
    float ls = 0.f;
    #pragma unroll
    for (int ii = 0; ii < 8; ++ii) {
        const int c = cg + 32 * ii;
        const size_t e = (size_t)bb * BCHW + (size_t)c * HW + hw0 + p4;
        const f32x4 zv = *(const f32x4*)(z + e);
        f32x4 v;
        v[0] = zq[p4 + 0][c]; v[1] = zq[p4 + 1][c];
        v[2] = zq[p4 + 2][c]; v[3] = zq[p4 + 3][c];
        *(f32x4*)(out + e) = v;
        const float d0 = v[0] - zv[0], d1 = v[1] - zv[1];
        const float d2 = v[2] - zv[2], d3 = v[3] - zv[3];
        ls += d0 * d0 + d1 * d1 + d2 * d2 + d3 * d3;
    }
    #pragma unroll
    for (int m = 1; m < 64; m <<= 1) ls += __shfl_xor(ls, m);
    if ((tid & 63) == 0) atomicAdd(loss, ls * (1.25f / 4194304.f));
}

// ---------------------------------------------------------------------------
extern "C" void kernel_launch(void* const* d_in, const int* in_sizes, int n_in,
                              void* d_out, int out_size, void* d_ws, size_t ws_size,
                              hipStream_t stream) {
    const float* z  = (const float*)d_in[0];
    const float* cb = (const float*)d_in[1];
    float* out  = (float*)d_out;
    float* idxf = out + 4194304;
    float* loss = out + 4210688;
    // scratch inside the z_q region of d_out (fully overwritten at the end):
    char* ob = (char*)d_out;
    short* zh    = (short*)ob;                    // [0 .. 8MB)   bf16 z [p][k]
    short* eh    = (short*)(ob + 8388608);        // [8 .. 12MB)  bf16 codebook
    u32*   best4 = (u32*)(ob + 12582912);         // [12 .. 16MB) 16384 x 16 x 4 u32

    char* ws = (char*)d_ws;
    u64*   final_ = (u64*)ws;                // 128 KB @ 0
    float* e2     = (float*)(ws + 131072);   // 32 KB

    hipMemsetAsync(final_, 0xFF, 131072, stream);
    hipMemsetAsync(loss, 0, 4, stream);

    vq_prep<<<2048, 256, 0, stream>>>(cb, eh, e2);
    vq_zh<<<dim3(16, 4, 16), 256, 0, stream>>>(z, zh);
    vq_gemm<<<dim3(NE / (NT * 128), NPIX / 128), 256, 0, stream>>>(zh, eh, best4);
    vq_exact<<<NPIX / 16, 256, 0, stream>>>(z, cb, e2, best4, final_);
    vq_out_kernel<<<NPIX / 32, 256, 0, stream>>>(z, cb, final_, out, idxf, loss);
}

// Round 15
// 199.409 us; speedup vs baseline: 52.6613x; 1.5122x over previous
//
#include <hip/hip_runtime.h>
#include <float.h>

#define NPIX 16384    // B*H*W pixels
#define NE   8192     // codebook entries
#define KD   256      // channels
#define HW   1024
#define BCHW 262144
#define NT   8        // N-tiles (128 codes) per wg -> wg spans 1024 codes (slice)
#define DELTA 2.5e-4f // rescue window: bf16 err + 2x key quant + margin
#define KMASK 0xFFFFE000u

typedef __attribute__((ext_vector_type(8))) short short8;
typedef __attribute__((ext_vector_type(4))) short short4v;
typedef __attribute__((ext_vector_type(4))) float f32x4;
typedef __attribute__((ext_vector_type(4))) unsigned int u32x4;
typedef unsigned long long u64;
typedef unsigned int u32;

__device__ __forceinline__ u32 fkey(float f) {
    u32 u = __float_as_uint(f);
    return u ^ ((u >> 31) ? 0xFFFFFFFFu : 0x80000000u);
}
__device__ __forceinline__ short bf16rne(float f) {
    u32 u = __float_as_uint(f);
    u += 0x7FFFu + ((u >> 16) & 1u);
    return (short)(u >> 16);
}
__device__ __forceinline__ float kval(u32 pk) {   // packed key -> quantized value
    return __uint_as_float(pk & KMASK);
}

#define GLDS(gp, lp) __builtin_amdgcn_global_load_lds( \
    (const __attribute__((address_space(1))) void*)(gp), \
    (__attribute__((address_space(3))) void*)(lp), 16, 0, 0)

// ---------------------------------------------------------------------------
// prep: codebook -> bf16 AND e2[n] = ||e_n||^2. One wave per row.
// ---------------------------------------------------------------------------
__global__ void vq_prep(const float* __restrict__ cb, short* __restrict__ eh,
                        float* __restrict__ e2) {
    const int row  = (blockIdx.x * 256 + threadIdx.x) >> 6;
    const int lane = threadIdx.x & 63;
    const f32x4 v = *(const f32x4*)(cb + (size_t)row * KD + lane * 4);
    short4v h;
    h[0] = bf16rne(v[0]); h[1] = bf16rne(v[1]);
    h[2] = bf16rne(v[2]); h[3] = bf16rne(v[3]);
    *(short4v*)(eh + (size_t)row * KD + lane * 4) = h;
    float s = v[0]*v[0] + v[1]*v[1] + v[2]*v[2] + v[3]*v[3];
    #pragma unroll
    for (int m = 1; m < 64; m <<= 1) s += __shfl_xor(s, m);
    if (lane == 0) e2[row] = s;
}

// ---------------------------------------------------------------------------
// z [b][k][hw] fp32 -> zh [p][k] bf16 (transpose via LDS)
// ---------------------------------------------------------------------------
__global__ void vq_zh(const float* __restrict__ z, short* __restrict__ zh) {
    __shared__ float ts[64][65];
    const int b   = blockIdx.z;
    const int k0  = blockIdx.y * 64;
    const int hw0 = blockIdx.x * 64;
    const int tid = threadIdx.x;
    const int pl  = tid & 63, kk = tid >> 6;
    #pragma unroll
    for (int i = 0; i < 16; ++i) {
        const int k = kk + 4 * i;
        ts[k][pl] = z[b * BCHW + (k0 + k) * HW + hw0 + pl];
    }
    __syncthreads();
    const int tx = tid & 15, ty = tid >> 4;
    #pragma unroll
    for (int j = 0; j < 4; ++j) {
        const int p = ty + 16 * j;
        short4v v;
        #pragma unroll
        for (int q = 0; q < 4; ++q) v[q] = bf16rne(ts[tx * 4 + q][p]);
        *(short4v*)(zh + (size_t)(b * HW + hw0 + p) * KD + k0 + tx * 4) = v;
    }
}

// ---------------------------------------------------------------------------
// Fused GEMM + per-(pixel, HALF-slice) top-4 tracking.
// GRID SWAPPED vs R14: blockIdx.x = pixel block (128), blockIdx.y = slice (8)
// so wgid%8 = pb%8 -> each zh pixel-block stays on ONE XCD's L2 (was: every
// block fetched by all 8 XCDs = 64 MB of refetch).
// Each (prow, hs=blockIdx.y*2+wn) has exactly ONE writer wave.
// ---------------------------------------------------------------------------
__global__ __launch_bounds__(256) void vq_gemm(
    const short* __restrict__ zh, const short* __restrict__ eh,
    u32* __restrict__ best4)
{
    __shared__ short As[2][4096];   // [buf][128 rows x 32 k]
    __shared__ short Bs[2][4096];

    const int tid  = threadIdx.x;
    const int lane = tid & 63;
    const int w    = tid >> 6;
    const int wm   = w >> 1, wn = w & 1;
    const int p0   = blockIdx.x * 128;
    const int nb0  = blockIdx.y * (NT * 128);

    const int sr = lane >> 2;
    const int ss = (lane & 3) ^ ((sr >> 1) & 3);
    const int q   = lane >> 4;
    const int rsw = ((lane & 15) >> 1) & 3;

    u32 b1[4][4], b2[4][4];
    #pragma unroll
    for (int m = 0; m < 4; ++m)
        #pragma unroll
        for (int r = 0; r < 4; ++r) { b1[m][r] = 0xFFFFFFFFu; b2[m][r] = 0xFFFFFFFFu; }

    #define STAGE(nt_, t_, buf_) do {                                          \
        const int k0_ = (t_) * 32;                                             \
        const int n0_ = nb0 + (nt_) * 128;                                     \
        _Pragma("unroll")                                                      \
        for (int i_ = 0; i_ < 2; ++i_) {                                       \
            const int rb_ = w * 32 + i_ * 16;                                  \
            GLDS(zh + (size_t)(p0 + rb_ + sr) * KD + k0_ + ss * 8,             \
                 &As[buf_][rb_ * 32]);                                         \
            GLDS(eh + (size_t)(n0_ + rb_ + sr) * KD + k0_ + ss * 8,            \
                 &Bs[buf_][rb_ * 32]);                                         \
        }                                                                      \
    } while (0)

    f32x4 acc[4][4];

    STAGE(0, 0, 0);
    __syncthreads();

    #pragma unroll 1
    for (int nt = 0; nt < NT; ++nt) {
        #pragma unroll
        for (int m = 0; m < 4; ++m)
            #pragma unroll
            for (int nf = 0; nf < 4; ++nf)
                acc[m][nf] = (f32x4){0.f, 0.f, 0.f, 0.f};

        #pragma unroll
        for (int t = 0; t < 8; ++t) {
            const int buf = t & 1;
            if (t < 7)            { STAGE(nt, t + 1, buf ^ 1); }
            else if (nt + 1 < NT) { STAGE(nt + 1, 0, buf ^ 1); }

            short8 af[4], bfv[4];
            #pragma unroll
            for (int m = 0; m < 4; ++m) {
                const int row = wm * 64 + m * 16 + (lane & 15);
                af[m] = *(const short8*)&As[buf][row * 32 + ((q ^ rsw) * 8)];
            }
            #pragma unroll
            for (int nf = 0; nf < 4; ++nf) {
                const int row = wn * 64 + nf * 16 + (lane & 15);
                bfv[nf] = *(const short8*)&Bs[buf][row * 32 + ((q ^ rsw) * 8)];
            }
            #pragma unroll
            for (int m = 0; m < 4; ++m)
                #pragma unroll
                for (int nf = 0; nf < 4; ++nf)
                    acc[m][nf] = __builtin_amdgcn_mfma_f32_16x16x32_bf16(
                        af[m], bfv[nf], acc[m][nf], 0, 0, 0);

            if (t == 7) {
                // ---- register-only best-2 merge (no shfl, no globals) ----
                const u32 nbase = (u32)(nb0 + nt * 128 + wn * 64 + (lane & 15));
                #pragma unroll
                for (int m = 0; m < 4; ++m) {
                    #pragma unroll
                    for (int r = 0; r < 4; ++r) {
                        u32 pk0 = (__float_as_uint(0.0625f - acc[m][0][r]) & KMASK) | (nbase);
                        u32 pk1 = (__float_as_uint(0.0625f - acc[m][1][r]) & KMASK) | (nbase + 16u);
                        u32 pk2 = (__float_as_uint(0.0625f - acc[m][2][r]) & KMASK) | (nbase + 32u);
                        u32 pk3 = (__float_as_uint(0.0625f - acc[m][3][r]) & KMASK) | (nbase + 48u);
                        const u32 lo01 = min(pk0, pk1), hi01 = max(pk0, pk1);
                        const u32 lo23 = min(pk2, pk3), hi23 = max(pk2, pk3);
                        const u32 m1 = min(lo01, lo23);
                        const u32 m2 = min(max(lo01, lo23), min(hi01, hi23));
                        const u32 nb1 = min(b1[m][r], m1);
                        const u32 nb2 = min(max(b1[m][r], m1), min(b2[m][r], m2));
                        b1[m][r] = nb1; b2[m][r] = nb2;
                    }
                }
            }
            __syncthreads();
        }
    }
    #undef STAGE

    // ---- wg-end: top-4 of this wave's 32-key lane-union per pixel ----
    const int g = lane >> 4;
    const int hs = blockIdx.y * 2 + wn;          // half-slice: single writer
    #pragma unroll
    for (int m = 0; m < 4; ++m) {
        #pragma unroll
        for (int r = 0; r < 4; ++r) {
            u32 a = b1[m][r], b = b2[m][r];
            u32 o[4];
            #pragma unroll
            for (int j = 0; j < 4; ++j) {
                u32 mm = a;
                #pragma unroll
                for (int msk = 1; msk < 16; msk <<= 1)
                    mm = min(mm, (u32)__shfl_xor((int)mm, msk));
                o[j] = mm;
                if (a == mm) { a = b; b = 0xFFFFFFFFu; }
            }
            if ((lane & 15) == 0) {
                const int prow = p0 + wm * 64 + m * 16 + g * 4 + r;
                u32x4 ov; ov[0] = o[0]; ov[1] = o[1]; ov[2] = o[2]; ov[3] = o[3];
                *(u32x4*)&best4[((size_t)prow * 16 + hs) * 4] = ov;
            }
        }
    }
}

// ---------------------------------------------------------------------------
// exact (parallel restructure): one wg per 16 pixels, 256 threads.
// Phase A: one THREAD per (pixel, half-slice): u32x4 key load, 16-lane
//          shfl group reduce (min/cnt/suspect). Direct-win if cnt==1 and
//          no truncation-suspect half-slice.
// Phase C: one THREAD per passer: serial f32x4 dot (z in LDS, cb via L1).
// Phase D: suspect half-slice: 256 threads x 2 codes, u64 wave-reduce.
// ---------------------------------------------------------------------------
__global__ __launch_bounds__(256) void vq_exact(
    const float* __restrict__ z, const float* __restrict__ cb,
    const float* __restrict__ e2, const u32* __restrict__ best4,
    u64* __restrict__ final_)
{
    __shared__ float zb[16][260];
    __shared__ u32 work[1024];     // (pix<<13) | n
    __shared__ u32 scans[256];     // (pix<<4) | hsx
    __shared__ int nwork, nscan;

    const int tid = threadIdx.x;
    const int g0  = blockIdx.x * 16;
    const int bb  = g0 >> 10, hw0 = g0 & 1023;
    const int pix = tid >> 4;
    const int hsx = tid & 15;

    if (tid == 0) { nwork = 0; nscan = 0; }
    __syncthreads();

    // Phase A ------------------------------------------------------------
    const u32x4 kv = *(const u32x4*)&best4[((size_t)(g0 + pix) * 16 + hsx) * 4];
    const u32 lmin = min(min(kv[0], kv[1]), min(kv[2], kv[3]));
    u32 mn = lmin;
    #pragma unroll
    for (int m = 1; m < 16; m <<= 1) mn = min(mn, (u32)__shfl_xor((int)mn, m));
    const float thr = kval(mn) + DELTA;
    const int c4 = (kval(kv[0]) <= thr ? 1 : 0) + (kval(kv[1]) <= thr ? 1 : 0)
                 + (kval(kv[2]) <= thr ? 1 : 0) + (kval(kv[3]) <= thr ? 1 : 0);
    int cnt = c4;
    #pragma unroll
    for (int m = 1; m < 16; m <<= 1) cnt += __shfl_xor(cnt, m);
    const int susp = (c4 == 4) ? 1 : 0;
    int anysusp = susp;
    #pragma unroll
    for (int m = 1; m < 16; m <<= 1) anysusp += __shfl_xor(anysusp, m);

    if (cnt == 1 && anysusp == 0) {
        if (lmin == mn) final_[g0 + pix] = (u64)(mn & 8191u);
    } else {
        if (c4 > 0) {
            const int base = atomicAdd(&nwork, c4);
            int k = 0;
            #pragma unroll
            for (int j = 0; j < 4; ++j)
                if (kval(kv[j]) <= thr)
                    work[base + (k++)] = ((u32)pix << 13) | (kv[j] & 8191u);
        }
        if (susp) scans[atomicAdd(&nscan, 1)] = ((u32)pix << 4) | (u32)hsx;
    }
    __syncthreads();
    const int nw = nwork, ns = nscan;
    if (nw == 0 && ns == 0) return;

    // Phase B: stage the 16-pixel z block coalesced ------------------------
    #pragma unroll
    for (int i = 0; i < 16; ++i) {
        const int idx = i * 256 + tid;
        const int c = idx >> 4, px = idx & 15;
        zb[px][c] = z[(size_t)bb * BCHW + (size_t)c * HW + hw0 + px];
    }
    __syncthreads();

    // Phase C: one thread per passer candidate ----------------------------
    for (int i = tid; i < nw; i += 256) {
        const u32 e = work[i];
        const int px = (int)(e >> 13), n = (int)(e & 8191u);
        const float* er = cb + (size_t)n * KD;
        float acc = 0.f;
        #pragma unroll 4
        for (int k = 0; k < KD; k += 4) {
            const f32x4 zv = *(const f32x4*)&zb[px][k];
            const f32x4 ev = *(const f32x4*)(er + k);
            acc += zv[0]*ev[0] + zv[1]*ev[1] + zv[2]*ev[2] + zv[3]*ev[3];
        }
        const float s = 0.5f * e2[n] - acc;
        atomicMin(&final_[g0 + px], ((u64)fkey(s) << 32) | (u32)n);
    }

    // Phase D: suspect half-slice scans (rare) ----------------------------
    for (int si = 0; si < ns; ++si) {
        const u32 e = scans[si];
        const int px = (int)(e >> 4), hx = (int)(e & 15u);
        u64 bku = ~0ULL;
        #pragma unroll
        for (int h = 0; h < 2; ++h) {
            const int ci = tid + h * 256;
            const int n = (hx >> 1) * 1024 + (ci >> 6) * 128
                        + (hx & 1) * 64 + (ci & 63);
            const float* er = cb + (size_t)n * KD;
            float acc = 0.f;
            #pragma unroll 4
            for (int k = 0; k < KD; k += 4) {
                const f32x4 zv = *(const f32x4*)&zb[px][k];
                const f32x4 ev = *(const f32x4*)(er + k);
                acc += zv[0]*ev[0] + zv[1]*ev[1] + zv[2]*ev[2] + zv[3]*ev[3];
            }
            const float s = 0.5f * e2[n] - acc;
            const u64 pk = ((u64)fkey(s) << 32) | (u32)n;
            bku = min(bku, pk);
        }
        #pragma unroll
        for (int m = 1; m < 64; m <<= 1) {
            const u64 o = (u64)__shfl_xor((long long)bku, m);
            bku = min(bku, o);
        }
        if ((tid & 63) == 0) atomicMin(&final_[g0 + px], bku);
    }
}

// ---------------------------------------------------------------------------
// Output kernel, tile-transposed.
// ---------------------------------------------------------------------------
__global__ __launch_bounds__(256) void vq_out_kernel(
    const float* __restrict__ z, const float* __restrict__ cb,
    const u64* __restrict__ final_, float* __restrict__ out,
    float* __restrict__ idxf, float* __restrict__ loss)
{
    __shared__ float zq[32][257];
    __shared__ int   nidx[32];

    const int tid = threadIdx.x;
    const int p0  = blockIdx.x * 32;
    const int bb  = p0 >> 10;
    const int hw0 = p0 & 1023;

    if (tid < 32) {
        const int n = (int)((u32)final_[p0 + tid] & 8191u);
        nidx[tid] = n;
        idxf[p0 + tid] = (float)n;
    }
    __syncthreads();

    {
        const int r = tid >> 3, i = tid & 7;
        const float* src = cb + (size_t)nidx[r] * KD;
        #pragma unroll
        for (int j = 0; j < 8; ++j) {
            const int col = i * 4 + j * 32;
            const f32x4 v = *(const f32x4*)(src + col);
            zq[r][col + 0] = v[0]; zq[r][col + 1] = v[1];
            zq[r][col + 2] = v[2]; zq[r][col + 3] = v[3];
        }
    }
    __syncthreads();

    const int p4 = (tid & 7) * 4;
    const int cg = tid >> 3;
    float ls = 0.f;
    #pragma unroll
    for (int ii = 0; ii < 8; ++ii) {
        const int c = cg + 32 * ii;
        const size_t e = (size_t)bb * BCHW + (size_t)c * HW + hw0 + p4;
        const f32x4 zv = *(const f32x4*)(z + e);
        f32x4 v;
        v[0] = zq[p4 + 0][c]; v[1] = zq[p4 + 1][c];
        v[2] = zq[p4 + 2][c]; v[3] = zq[p4 + 3][c];
        *(f32x4*)(out + e) = v;
        const float d0 = v[0] - zv[0], d1 = v[1] - zv[1];
        const float d2 = v[2] - zv[2], d3 = v[3] - zv[3];
        ls += d0 * d0 + d1 * d1 + d2 * d2 + d3 * d3;
    }
    #pragma unroll
    for (int m = 1; m < 64; m <<= 1) ls += __shfl_xor(ls, m);
    if ((tid & 63) == 0) atomicAdd(loss, ls * (1.25f / 4194304.f));
}

// ---------------------------------------------------------------------------
extern "C" void kernel_launch(void* const* d_in, const int* in_sizes, int n_in,
                              void* d_out, int out_size, void* d_ws, size_t ws_size,
                              hipStream_t stream) {
    const float* z  = (const float*)d_in[0];
    const float* cb = (const float*)d_in[1];
    float* out  = (float*)d_out;
    float* idxf = out + 4194304;
    float* loss = out + 4210688;
    // scratch inside the z_q region of d_out (fully overwritten at the end):
    char* ob = (char*)d_out;
    short* zh    = (short*)ob;                    // [0 .. 8MB)   bf16 z [p][k]
    short* eh    = (short*)(ob + 8388608);        // [8 .. 12MB)  bf16 codebook
    u32*   best4 = (u32*)(ob + 12582912);         // [12 .. 16MB) 16384 x 16 x 4 u32

    char* ws = (char*)d_ws;
    u64*   final_ = (u64*)ws;                // 128 KB @ 0
    float* e2     = (float*)(ws + 131072);   // 32 KB

    hipMemsetAsync(final_, 0xFF, 131072, stream);
    hipMemsetAsync(loss, 0, 4, stream);

    vq_prep<<<2048, 256, 0, stream>>>(cb, eh, e2);
    vq_zh<<<dim3(16, 4, 16), 256, 0, stream>>>(z, zh);
    vq_gemm<<<dim3(NPIX / 128, NE / (NT * 128)), 256, 0, stream>>>(zh, eh, best4);
    vq_exact<<<NPIX / 16, 256, 0, stream>>>(z, cb, e2, best4, final_);
    vq_out_kernel<<<NPIX / 32, 256, 0, stream>>>(z, cb, final_, out, idxf, loss);
}